// Round 7
// baseline (248.327 us; speedup 1.0000x reference)
//
#include <hip/hip_runtime.h>
#include <hip/hip_cooperative_groups.h>

#define B_ 4
#define L_ 512
#define D_ 100

namespace cg = cooperative_groups;

__device__ __forceinline__ float fexp2(float x) { return __builtin_amdgcn_exp2f(x); }
__device__ __forceinline__ float frcp(float x)  { return __builtin_amdgcn_rcpf(x); }

// LDS union: max(P1)=52224 B -> 3 blocks/CU (156672 <= 163840)
struct P1 { float2 XQ[32 * 102]; float2 XK[32 * 102]; };          // 52224 B
struct P2 { float c[4][3]; float P[4][512]; float R[2][4][128]; }; // 12336 B
struct P3 { float xs[20 * 104]; float wl[30 * 304]; };             // 44800 B
union SU { P1 p1; P2 p2; P3 p3; };

// ---------------------------------------------------------------------------
// Phase 1: one 32x32 upper-tri tile (kt>=qt) per job (136 per batch, 544 all).
//   s = dot(x_q,x_k); t = sum_d tanh(x_q+x_k) via exp-product (1 rcp/elem).
//   Stores S,T (direct + mirror via LDS transpose) and Zp row/col partial
//   sums of e1=exp2(s*L2E-120), e2=exp2(t*L2E-32), e3=exp2(s*L2E/10)
//   (fixed offsets, no max pass -- bounds argued in round 2).
// ---------------------------------------------------------------------------
__device__ void phase1_tile(int job, const float* __restrict__ x,
                            float* __restrict__ S, float* __restrict__ T,
                            float* __restrict__ Zp, SU& u) {
  int b, qt, kt;
  if (job < 480) {  // off-diagonal tiles: 120 per batch
    b = job / 120;
    int r = job - b * 120;
    qt = 0;
    while (r >= 15 - qt) { r -= 15 - qt; ++qt; }
    kt = qt + 1 + r;
  } else {          // diagonal tiles: 16 per batch
    int dj = job - 480;
    b = dj >> 4;
    qt = kt = dj & 15;
  }
  const bool diag = (kt == qt);
  const int tid = threadIdx.x;
  const float C = 2.8853900817779268f;  // 2*log2(e)
  const float L2E = 1.4426950408889634f;
  const float* xb = x + (size_t)b * L_ * D_;
  for (int i = tid; i < 32 * D_; i += 256) {
    int r = i / D_, c = i - r * D_;
    float xq = xb[(qt * 32 + r) * D_ + c];
    u.p1.XQ[r * 102 + c] = make_float2(xq, fexp2(xq * C));
    if (!diag) {
      float xk = xb[(kt * 32 + r) * D_ + c];
      u.p1.XK[r * 102 + c] = make_float2(xk, fexp2(xk * C));
    }
  }
  __syncthreads();
  const float2* XKp = diag ? u.p1.XQ : u.p1.XK;
  const int tx = tid & 15, ty = tid >> 4;
  float s00 = 0, s01 = 0, s10 = 0, s11 = 0;
  float r00 = 0, r01 = 0, r10 = 0, r11 = 0;
  const float2* qp0 = &u.p1.XQ[ty * 102];
  const float2* qp1 = &u.p1.XQ[(ty + 16) * 102];
  const float2* kp0 = &XKp[tx * 102];
  const float2* kp1 = &XKp[(tx + 16) * 102];
#pragma unroll 2
  for (int d = 0; d < D_; d += 2) {  // 2 d per iter via float4 (b128) reads
    float4 A0 = *(const float4*)&qp0[d];
    float4 A1 = *(const float4*)&qp1[d];
    float4 B0 = *(const float4*)&kp0[d];
    float4 B1 = *(const float4*)&kp1[d];
    s00 += A0.x * B0.x + A0.z * B0.z;
    s01 += A0.x * B1.x + A0.z * B1.z;
    s10 += A1.x * B0.x + A1.z * B0.z;
    s11 += A1.x * B1.x + A1.z * B1.z;
    r00 += frcp(fmaf(A0.y, B0.y, 1.0f)) + frcp(fmaf(A0.w, B0.w, 1.0f));
    r01 += frcp(fmaf(A0.y, B1.y, 1.0f)) + frcp(fmaf(A0.w, B1.w, 1.0f));
    r10 += frcp(fmaf(A1.y, B0.y, 1.0f)) + frcp(fmaf(A1.w, B0.w, 1.0f));
    r11 += frcp(fmaf(A1.y, B1.y, 1.0f)) + frcp(fmaf(A1.w, B1.w, 1.0f));
  }
  float t00 = (float)D_ - 2.0f * r00;
  float t01 = (float)D_ - 2.0f * r01;
  float t10 = (float)D_ - 2.0f * r10;
  float t11 = (float)D_ - 2.0f * r11;
  // e's for Zp partials only (S,T are what get stored)
  float e1_00 = fexp2(fmaf(s00, L2E, -120.0f)), e1_01 = fexp2(fmaf(s01, L2E, -120.0f));
  float e1_10 = fexp2(fmaf(s10, L2E, -120.0f)), e1_11 = fexp2(fmaf(s11, L2E, -120.0f));
  float e2_00 = fexp2(fmaf(t00, L2E, -32.0f)),  e2_01 = fexp2(fmaf(t01, L2E, -32.0f));
  float e2_10 = fexp2(fmaf(t10, L2E, -32.0f)),  e2_11 = fexp2(fmaf(t11, L2E, -32.0f));
  const float L2E10 = 0.14426950408889634f;
  float e3_00 = fexp2(s00 * L2E10), e3_01 = fexp2(s01 * L2E10);
  float e3_10 = fexp2(s10 * L2E10), e3_11 = fexp2(s11 * L2E10);

  const int q0r = qt * 32 + ty, q1r = q0r + 16;
  const int k0 = kt * 32 + tx, k1 = k0 + 16;
  float* Sb = S + (size_t)b * L_ * L_;
  float* Tb = T + (size_t)b * L_ * L_;
  Sb[q0r * L_ + k0] = s00; Sb[q0r * L_ + k1] = s01;
  Sb[q1r * L_ + k0] = s10; Sb[q1r * L_ + k1] = s11;
  Tb[q0r * L_ + k0] = t00; Tb[q0r * L_ + k1] = t01;
  Tb[q1r * L_ + k0] = t10; Tb[q1r * L_ + k1] = t11;

  // ---- row Zp partials (reduce e-sums over tx within wave)
  float rs[3][2];
  rs[0][0] = e1_00 + e1_01; rs[0][1] = e1_10 + e1_11;
  rs[1][0] = e2_00 + e2_01; rs[1][1] = e2_10 + e2_11;
  rs[2][0] = e3_00 + e3_01; rs[2][1] = e3_10 + e3_11;
#pragma unroll
  for (int o = 8; o > 0; o >>= 1) {
#pragma unroll
    for (int e = 0; e < 3; ++e) {
      rs[e][0] += __shfl_xor(rs[e][0], o);
      rs[e][1] += __shfl_xor(rs[e][1], o);
    }
  }
  if (tx == 0) {
#pragma unroll
    for (int e = 0; e < 3; ++e) {
      Zp[(((size_t)b * L_ + q0r) * 16 + kt) * 3 + e] = rs[e][0];
      Zp[(((size_t)b * L_ + q1r) * 16 + kt) * 3 + e] = rs[e][1];
    }
  }

  if (diag) return;

  // ---- column Zp partials (mirror rows): shuffles over ty bits then LDS
  float cs_[3][2];
  cs_[0][0] = e1_00 + e1_10; cs_[0][1] = e1_01 + e1_11;
  cs_[1][0] = e2_00 + e2_10; cs_[1][1] = e2_01 + e2_11;
  cs_[2][0] = e3_00 + e3_10; cs_[2][1] = e3_01 + e3_11;
#pragma unroll
  for (int o = 16; o <= 32; o <<= 1) {
#pragma unroll
    for (int e = 0; e < 3; ++e) {
      cs_[e][0] += __shfl_xor(cs_[e][0], o);
      cs_[e][1] += __shfl_xor(cs_[e][1], o);
    }
  }
  __syncthreads();  // all d-loop reads of XK complete before aliasing
  float* xkf = (float*)u.p1.XK;   // reuse XK space
  float* M = xkf;                 // 32*33 = 1056 floats (transpose buffer)
  float* colred = xkf + 1104;     // 4*16*6 = 384 floats
  const int wv = tid >> 6, lane = tid & 63;
  if ((lane >> 4) == 0) {
#pragma unroll
    for (int e = 0; e < 3; ++e) {
      colred[wv * 96 + tx * 6 + e * 2 + 0] = cs_[e][0];
      colred[wv * 96 + tx * 6 + e * 2 + 1] = cs_[e][1];
    }
  }
  __syncthreads();  // colred ready
  if (tid < 96) {
    int txx = tid / 6, j = tid - txx * 6;
    float v = colred[0 * 96 + txx * 6 + j] + colred[1 * 96 + txx * 6 + j] +
              colred[2 * 96 + txx * 6 + j] + colred[3 * 96 + txx * 6 + j];
    int e = j >> 1, half = j & 1;
    int krow = kt * 32 + txx + half * 16;
    Zp[(((size_t)b * L_ + krow) * 16 + qt) * 3 + e] = v;
  }
  // ---- mirror stores via LDS transpose (coalesced rows); M disjoint from colred
  const int mo = ty * 33 + tx;
  M[mo] = s00; M[mo + 16] = s01;
  M[mo + 16 * 33] = s10; M[mo + 16 * 33 + 16] = s11;
  __syncthreads();
#pragma unroll
  for (int j = 0; j < 4; ++j) {
    int idx = tid + 256 * j, kr = idx >> 5, qc = idx & 31;
    Sb[(kt * 32 + kr) * L_ + qt * 32 + qc] = M[qc * 33 + kr];
  }
  __syncthreads();
  M[mo] = t00; M[mo + 16] = t01;
  M[mo + 16 * 33] = t10; M[mo + 16 * 33 + 16] = t11;
  __syncthreads();
#pragma unroll
  for (int j = 0; j < 4; ++j) {
    int idx = tid + 256 * j, kr = idx >> 5, qc = idx & 31;
    Tb[(kt * 32 + kr) * L_ + qt * 32 + qc] = M[qc * 33 + kr];
  }
}

// ---------------------------------------------------------------------------
// Phase 2: 512 jobs of 4 q-rows, full k. c_i from Zp; P formed in LDS from
// S,T on the fly (3 exps/elem, bit-identical to phase 1's Zp path); PV with
// 2-way k-split; X2 = src + attn.
// BUG FIX (round 7, root cause of rounds 4-6): the X2 writeback needs
// 4*D_=400 lanes but the block has 256 -> was `if (tid < 4*D_)`, leaving
// rows 2-3 of every group unwritten (workspace poison). Now a strided loop.
// ---------------------------------------------------------------------------
__device__ void phase2_job(int job, const float* __restrict__ x,
                           const float* __restrict__ S, const float* __restrict__ T,
                           const float* __restrict__ Zp, const float* __restrict__ attw,
                           float* __restrict__ X2, SU& u) {
  const int tid = threadIdx.x;
  const int b = job >> 7, q0 = (job & 127) * 4;
  if (tid < 12) {
    int row = tid / 3, j = tid - row * 3;
    const float* zp = Zp + (((size_t)b * L_ + q0 + row) * 16) * 3 + j;
    float z = 0.0f;
#pragma unroll
    for (int t = 0; t < 16; ++t) z += zp[t * 3];
    float winv = frcp(attw[0] + attw[1] + attw[2]);
    u.p2.c[row][j] = attw[j] * winv * frcp(z);
  }
  __syncthreads();
  const float L2E = 1.4426950408889634f, L2E10 = 0.14426950408889634f;
  for (int i = tid; i < 4 * 512; i += 256) {
    int row = i >> 9, kk = i & 511;
    size_t o = ((size_t)b * L_ + q0 + row) * (size_t)L_ + kk;
    float s = S[o], t = T[o];
    float e1 = fexp2(fmaf(s, L2E, -120.0f));
    float e2 = fexp2(fmaf(t, L2E, -32.0f));
    float e3 = fexp2(s * L2E10);
    u.p2.P[row][kk] = u.p2.c[row][0] * e1 + u.p2.c[row][1] * e2 + u.p2.c[row][2] * e3;
  }
  __syncthreads();
  const int d = tid & 127, kh = tid >> 7;
  float a0 = 0, a1 = 0, a2 = 0, a3 = 0;
  if (d < D_) {
    const float* xb = x + ((size_t)b * L_ + kh * 256) * D_;
    for (int g = 0; g < 64; ++g) {
      int kk = kh * 256 + g * 4;
      float4 p0 = *(const float4*)&u.p2.P[0][kk];
      float4 p1 = *(const float4*)&u.p2.P[1][kk];
      float4 p2 = *(const float4*)&u.p2.P[2][kk];
      float4 p3 = *(const float4*)&u.p2.P[3][kk];
      float x0 = xb[(g * 4 + 0) * D_ + d];
      float x1 = xb[(g * 4 + 1) * D_ + d];
      float x2 = xb[(g * 4 + 2) * D_ + d];
      float x3 = xb[(g * 4 + 3) * D_ + d];
      a0 += p0.x * x0 + p0.y * x1 + p0.z * x2 + p0.w * x3;
      a1 += p1.x * x0 + p1.y * x1 + p1.z * x2 + p1.w * x3;
      a2 += p2.x * x0 + p2.y * x1 + p2.z * x2 + p2.w * x3;
      a3 += p3.x * x0 + p3.y * x1 + p3.z * x2 + p3.w * x3;
    }
  }
  __syncthreads();  // P reads done (R is a separate member, but keep ordering)
  u.p2.R[kh][0][d] = a0; u.p2.R[kh][1][d] = a1;
  u.p2.R[kh][2][d] = a2; u.p2.R[kh][3][d] = a3;
  __syncthreads();
  for (int i = tid; i < 4 * D_; i += 256) {   // FIX: was `if (tid < 4*D_)`
    int row = i / D_, dd = i - row * D_;
    size_t o = ((size_t)b * L_ + q0 + row) * D_ + dd;
    X2[o] = x[o] + u.p2.R[0][row][dd] + u.p2.R[1][row][dd];
  }
}

// ---------------------------------------------------------------------------
// Phase 3: 128 jobs = 32 t-tiles (16 wide, tile 31 handles tail t=512,513) x B.
// All 30 channels per block; zero-padded right-aligned ws=3 weights; ReLU +
// max-pool with shuffle reduce + device atomicMax into pooled.
// ---------------------------------------------------------------------------
__device__ void phase3_job(int job, const float* __restrict__ X2,
    const float* __restrict__ w1, const float* __restrict__ b1,
    const float* __restrict__ w2, const float* __restrict__ b2,
    const float* __restrict__ w3, const float* __restrict__ b3,
    float* __restrict__ pooled, SU& u) {
  const int tid = threadIdx.x;
  const int b = job >> 5, tt = job & 31;
  const int t0 = tt * 16;
  const float* xb = X2 + (size_t)b * L_ * D_;
  for (int i = tid; i < 20 * D_; i += 256) {
    int r = i / D_, c = i - r * D_;
    int rg = t0 - 2 + r;
    u.p3.xs[r * 104 + c] = (rg >= 0 && rg < L_) ? xb[(size_t)rg * D_ + c] : 0.0f;
  }
  for (int i = tid; i < 30 * 300; i += 256) {
    int c = i / 300, rest = i - c * 300;
    int h = rest / D_, dd = rest - h * D_;
    int ws = 1 + c / 10;
    int hh = h - (3 - ws);
    float wv = 0.0f;
    if (hh >= 0) {
      if (ws == 1)      wv = w1[c * D_ + dd];
      else if (ws == 2) wv = w2[(c - 10) * 2 * D_ + hh * D_ + dd];
      else              wv = w3[(c - 20) * 3 * D_ + hh * D_ + dd];
    }
    u.p3.wl[c * 304 + h * D_ + dd] = wv;
  }
  __syncthreads();
  const int tl = tid & 15, cgi = tid >> 4;
  const int c0 = cgi, c1 = cgi + 16;
  float vm0 = 0.0f, vm1 = 0.0f;
  const int nrep = (tt == 31) ? 2 : 1;
  for (int rep = 0; rep < nrep; ++rep) {
    int t = t0 + rep * 16 + tl;
    if (t > L_ + 1) continue;
    float acc0 = 0, acc1 = 0;
#pragma unroll
    for (int h = 0; h < 3; ++h) {
      const float4* xr  = (const float4*)&u.p3.xs[(rep * 16 + tl + h) * 104];
      const float4* wr0 = (const float4*)&u.p3.wl[c0 * 304 + h * D_];
      const float4* wr1 = (const float4*)&u.p3.wl[c1 * 304 + h * D_];
#pragma unroll 5
      for (int j = 0; j < 25; ++j) {
        float4 xv = xr[j];
        float4 w0v = wr0[j];
        acc0 += xv.x * w0v.x + xv.y * w0v.y + xv.z * w0v.z + xv.w * w0v.w;
        if (c1 < 30) {
          float4 w1v = wr1[j];
          acc1 += xv.x * w1v.x + xv.y * w1v.y + xv.z * w1v.z + xv.w * w1v.w;
        }
      }
    }
    {
      int wsz = 1 + c0 / 10;
      float bias = (wsz == 1) ? b1[c0] : (wsz == 2 ? b2[c0 - 10] : b3[c0 - 20]);
      if (t < L_ + wsz - 1) vm0 = fmaxf(vm0, fmaxf(acc0 + bias, 0.0f));
    }
    if (c1 < 30) {
      int wsz = 1 + c1 / 10;
      float bias = (wsz == 1) ? b1[c1] : (wsz == 2 ? b2[c1 - 10] : b3[c1 - 20]);
      if (t < L_ + wsz - 1) vm1 = fmaxf(vm1, fmaxf(acc1 + bias, 0.0f));
    }
  }
#pragma unroll
  for (int o = 8; o > 0; o >>= 1) {
    vm0 = fmaxf(vm0, __shfl_xor(vm0, o));
    vm1 = fmaxf(vm1, __shfl_xor(vm1, o));
  }
  if (tl == 0) {
    atomicMax(reinterpret_cast<int*>(&pooled[b * 30 + c0]), __float_as_int(vm0));
    if (c1 < 30)
      atomicMax(reinterpret_cast<int*>(&pooled[b * 30 + c1]), __float_as_int(vm1));
  }
}

__device__ void phase4_linear(float* __restrict__ pooled,
                              const float* __restrict__ lw,
                              const float* __restrict__ lb,
                              float* __restrict__ out) {
  int i = threadIdx.x;
  if (i >= B_ * 2) return;
  int bb = i >> 1, j = i & 1;
  float acc = lb[j];
  int* pI = reinterpret_cast<int*>(pooled);
#pragma unroll
  for (int c = 0; c < 30; ++c) {
    float pv = __int_as_float(atomicMax(&pI[bb * 30 + c], 0));  // coherent read, v>=0
    acc = fmaf(pv, lw[c * 2 + j], acc);
  }
  out[bb * 2 + j] = acc;
}

// ---------------------------------------------------------------------------
// Fused cooperative kernel: 544 blocks x 256 threads, 3 grid syncs.
// ---------------------------------------------------------------------------
__global__ __launch_bounds__(256, 3) void k_fused(
    const float* __restrict__ x, const float* __restrict__ attw,
    const float* __restrict__ w1, const float* __restrict__ b1,
    const float* __restrict__ w2, const float* __restrict__ b2,
    const float* __restrict__ w3, const float* __restrict__ b3,
    const float* __restrict__ lw, const float* __restrict__ lb,
    float* S, float* T, float* Zp, float* X2, float* pooled, float* out) {
  __shared__ SU u;
  cg::grid_group grid = cg::this_grid();
  const int bid = blockIdx.x;
  if (bid == 0 && threadIdx.x < B_ * 30) pooled[threadIdx.x] = 0.0f;
  phase1_tile(bid, x, S, T, Zp, u);
  grid.sync();
  if (bid < 512) phase2_job(bid, x, S, T, Zp, attw, X2, u);
  grid.sync();
  if (bid < 128) phase3_job(bid, X2, w1, b1, w2, b2, w3, b3, pooled, u);
  grid.sync();
  if (bid == 0) phase4_linear(pooled, lw, lb, out);
}

// ---------------------------------------------------------------------------
// Fallback plain-launch pipeline (used only if cooperative launch errors)
// ---------------------------------------------------------------------------
__global__ __launch_bounds__(256, 3) void fb_p1(const float* __restrict__ x,
    float* S, float* T, float* Zp, float* pooled) {
  __shared__ SU u;
  if (blockIdx.x == 0 && threadIdx.x < B_ * 30) pooled[threadIdx.x] = 0.0f;
  phase1_tile(blockIdx.x, x, S, T, Zp, u);
}
__global__ __launch_bounds__(256, 3) void fb_p2(const float* __restrict__ x,
    const float* S, const float* T, const float* Zp, const float* attw, float* X2) {
  __shared__ SU u;
  phase2_job(blockIdx.x, x, S, T, Zp, attw, X2, u);
}
__global__ __launch_bounds__(256, 3) void fb_p3(const float* __restrict__ X2,
    const float* w1, const float* b1, const float* w2, const float* b2,
    const float* w3, const float* b3, float* pooled) {
  __shared__ SU u;
  phase3_job(blockIdx.x, X2, w1, b1, w2, b2, w3, b3, pooled, u);
}
__global__ void fb_p4(float* pooled, const float* lw, const float* lb, float* out) {
  phase4_linear(pooled, lw, lb, out);
}

extern "C" void kernel_launch(void* const* d_in, const int* in_sizes, int n_in,
                              void* d_out, int out_size, void* d_ws, size_t ws_size,
                              hipStream_t stream) {
  const float* src  = (const float*)d_in[0];
  const float* attw = (const float*)d_in[1];
  const float* w1   = (const float*)d_in[2];
  const float* b1   = (const float*)d_in[3];
  const float* w2   = (const float*)d_in[4];
  const float* b2   = (const float*)d_in[5];
  const float* w3   = (const float*)d_in[6];
  const float* b3   = (const float*)d_in[7];
  const float* lw   = (const float*)d_in[8];
  const float* lb   = (const float*)d_in[9];

  // ws: S | T (1,048,576 f32 each) | Zp (98,304) | X2 (204,800) | pooled (128)
  float* S  = (float*)d_ws;
  float* T  = S + (size_t)B_ * L_ * L_;
  float* Zp = T + (size_t)B_ * L_ * L_;
  float* X2 = Zp + (size_t)B_ * L_ * 16 * 3;
  float* PL = X2 + (size_t)B_ * L_ * D_;
  float* out = (float*)d_out;

  void* args[] = {
    (void*)&src, (void*)&attw, (void*)&w1, (void*)&b1, (void*)&w2, (void*)&b2,
    (void*)&w3, (void*)&b3, (void*)&lw, (void*)&lb,
    (void*)&S, (void*)&T, (void*)&Zp, (void*)&X2, (void*)&PL, (void*)&out
  };
  hipError_t err = hipLaunchCooperativeKernel((void*)k_fused, dim3(544), dim3(256),
                                              args, 0, stream);
  if (err != hipSuccess) {
    hipLaunchKernelGGL(fb_p1, dim3(544), dim3(256), 0, stream, src, S, T, Zp, PL);
    hipLaunchKernelGGL(fb_p2, dim3(512), dim3(256), 0, stream, src, S, T, Zp, attw, X2);
    hipLaunchKernelGGL(fb_p3, dim3(128), dim3(256), 0, stream, X2, w1, b1, w2, b2, w3, b3, PL);
    hipLaunchKernelGGL(fb_p4, dim3(1), dim3(64), 0, stream, PL, lw, lb, out);
  }
}

// Round 8
// 159.910 us; speedup vs baseline: 1.5529x; 1.5529x over previous
//
#include <hip/hip_runtime.h>

#define B_ 4
#define L_ 512
#define D_ 100
#define NB_ 544
#define MAGIC_ 0x5ca1ab1e

__device__ __forceinline__ float fexp2(float x) { return __builtin_amdgcn_exp2f(x); }
__device__ __forceinline__ float frcp(float x)  { return __builtin_amdgcn_rcpf(x); }

// LDS union: max(P1)=52224 B -> 3 blocks/CU (156672 <= 163840) => all 544
// blocks of the grid are co-resident => in-kernel spin barrier is safe.
struct P1 { float2 XQ[32 * 102]; float2 XK[32 * 102]; };          // 52224 B
struct P2 { float c[4][3]; float P[4][512]; float R[2][4][128]; }; // 12336 B
struct P3 { float xs[20 * 104]; float wl[30 * 304]; };             // 44800 B
union SU { P1 p1; P2 p2; P3 p3; };

// ---------------------------------------------------------------------------
// Hand-rolled grid barrier (vs cg::grid.sync which cost ~70us/sync in round 7):
// release fence only on the single fetch_add; RELAXED polls with s_sleep
// backoff (no buffer_inv per poll); one ACQUIRE load after the spin.
// ---------------------------------------------------------------------------
__device__ __forceinline__ void grid_barrier(int* cnt) {
  __syncthreads();
  if (threadIdx.x == 0) {
    __hip_atomic_fetch_add(cnt, 1, __ATOMIC_RELEASE, __HIP_MEMORY_SCOPE_AGENT);
    while (__hip_atomic_load(cnt, __ATOMIC_RELAXED, __HIP_MEMORY_SCOPE_AGENT) < NB_)
      __builtin_amdgcn_s_sleep(4);
    (void)__hip_atomic_load(cnt, __ATOMIC_ACQUIRE, __HIP_MEMORY_SCOPE_AGENT);
  }
  __syncthreads();
}

// ---------------------------------------------------------------------------
// Phase 1 (validated round 7): one 32x32 upper-tri tile per job.
// ---------------------------------------------------------------------------
__device__ void phase1_tile(int job, const float* __restrict__ x,
                            float* __restrict__ S, float* __restrict__ T,
                            float* __restrict__ Zp, SU& u) {
  int b, qt, kt;
  if (job < 480) {  // off-diagonal tiles: 120 per batch
    b = job / 120;
    int r = job - b * 120;
    qt = 0;
    while (r >= 15 - qt) { r -= 15 - qt; ++qt; }
    kt = qt + 1 + r;
  } else {          // diagonal tiles: 16 per batch
    int dj = job - 480;
    b = dj >> 4;
    qt = kt = dj & 15;
  }
  const bool diag = (kt == qt);
  const int tid = threadIdx.x;
  const float C = 2.8853900817779268f;  // 2*log2(e)
  const float L2E = 1.4426950408889634f;
  const float* xb = x + (size_t)b * L_ * D_;
  for (int i = tid; i < 32 * D_; i += 256) {
    int r = i / D_, c = i - r * D_;
    float xq = xb[(qt * 32 + r) * D_ + c];
    u.p1.XQ[r * 102 + c] = make_float2(xq, fexp2(xq * C));
    if (!diag) {
      float xk = xb[(kt * 32 + r) * D_ + c];
      u.p1.XK[r * 102 + c] = make_float2(xk, fexp2(xk * C));
    }
  }
  __syncthreads();
  const float2* XKp = diag ? u.p1.XQ : u.p1.XK;
  const int tx = tid & 15, ty = tid >> 4;
  float s00 = 0, s01 = 0, s10 = 0, s11 = 0;
  float r00 = 0, r01 = 0, r10 = 0, r11 = 0;
  const float2* qp0 = &u.p1.XQ[ty * 102];
  const float2* qp1 = &u.p1.XQ[(ty + 16) * 102];
  const float2* kp0 = &XKp[tx * 102];
  const float2* kp1 = &XKp[(tx + 16) * 102];
#pragma unroll 2
  for (int d = 0; d < D_; d += 2) {  // 2 d per iter via float4 (b128) reads
    float4 A0 = *(const float4*)&qp0[d];
    float4 A1 = *(const float4*)&qp1[d];
    float4 B0 = *(const float4*)&kp0[d];
    float4 B1 = *(const float4*)&kp1[d];
    s00 += A0.x * B0.x + A0.z * B0.z;
    s01 += A0.x * B1.x + A0.z * B1.z;
    s10 += A1.x * B0.x + A1.z * B0.z;
    s11 += A1.x * B1.x + A1.z * B1.z;
    r00 += frcp(fmaf(A0.y, B0.y, 1.0f)) + frcp(fmaf(A0.w, B0.w, 1.0f));
    r01 += frcp(fmaf(A0.y, B1.y, 1.0f)) + frcp(fmaf(A0.w, B1.w, 1.0f));
    r10 += frcp(fmaf(A1.y, B0.y, 1.0f)) + frcp(fmaf(A1.w, B0.w, 1.0f));
    r11 += frcp(fmaf(A1.y, B1.y, 1.0f)) + frcp(fmaf(A1.w, B1.w, 1.0f));
  }
  float t00 = (float)D_ - 2.0f * r00;
  float t01 = (float)D_ - 2.0f * r01;
  float t10 = (float)D_ - 2.0f * r10;
  float t11 = (float)D_ - 2.0f * r11;
  float e1_00 = fexp2(fmaf(s00, L2E, -120.0f)), e1_01 = fexp2(fmaf(s01, L2E, -120.0f));
  float e1_10 = fexp2(fmaf(s10, L2E, -120.0f)), e1_11 = fexp2(fmaf(s11, L2E, -120.0f));
  float e2_00 = fexp2(fmaf(t00, L2E, -32.0f)),  e2_01 = fexp2(fmaf(t01, L2E, -32.0f));
  float e2_10 = fexp2(fmaf(t10, L2E, -32.0f)),  e2_11 = fexp2(fmaf(t11, L2E, -32.0f));
  const float L2E10 = 0.14426950408889634f;
  float e3_00 = fexp2(s00 * L2E10), e3_01 = fexp2(s01 * L2E10);
  float e3_10 = fexp2(s10 * L2E10), e3_11 = fexp2(s11 * L2E10);

  const int q0r = qt * 32 + ty, q1r = q0r + 16;
  const int k0 = kt * 32 + tx, k1 = k0 + 16;
  float* Sb = S + (size_t)b * L_ * L_;
  float* Tb = T + (size_t)b * L_ * L_;
  Sb[q0r * L_ + k0] = s00; Sb[q0r * L_ + k1] = s01;
  Sb[q1r * L_ + k0] = s10; Sb[q1r * L_ + k1] = s11;
  Tb[q0r * L_ + k0] = t00; Tb[q0r * L_ + k1] = t01;
  Tb[q1r * L_ + k0] = t10; Tb[q1r * L_ + k1] = t11;

  // ---- row Zp partials (reduce e-sums over tx within wave)
  float rs[3][2];
  rs[0][0] = e1_00 + e1_01; rs[0][1] = e1_10 + e1_11;
  rs[1][0] = e2_00 + e2_01; rs[1][1] = e2_10 + e2_11;
  rs[2][0] = e3_00 + e3_01; rs[2][1] = e3_10 + e3_11;
#pragma unroll
  for (int o = 8; o > 0; o >>= 1) {
#pragma unroll
    for (int e = 0; e < 3; ++e) {
      rs[e][0] += __shfl_xor(rs[e][0], o);
      rs[e][1] += __shfl_xor(rs[e][1], o);
    }
  }
  if (tx == 0) {
#pragma unroll
    for (int e = 0; e < 3; ++e) {
      Zp[(((size_t)b * L_ + q0r) * 16 + kt) * 3 + e] = rs[e][0];
      Zp[(((size_t)b * L_ + q1r) * 16 + kt) * 3 + e] = rs[e][1];
    }
  }

  if (diag) return;

  // ---- column Zp partials (mirror rows): shuffles over ty bits then LDS
  float cs_[3][2];
  cs_[0][0] = e1_00 + e1_10; cs_[0][1] = e1_01 + e1_11;
  cs_[1][0] = e2_00 + e2_10; cs_[1][1] = e2_01 + e2_11;
  cs_[2][0] = e3_00 + e3_10; cs_[2][1] = e3_01 + e3_11;
#pragma unroll
  for (int o = 16; o <= 32; o <<= 1) {
#pragma unroll
    for (int e = 0; e < 3; ++e) {
      cs_[e][0] += __shfl_xor(cs_[e][0], o);
      cs_[e][1] += __shfl_xor(cs_[e][1], o);
    }
  }
  __syncthreads();  // all d-loop reads of XK complete before aliasing
  float* xkf = (float*)u.p1.XK;   // reuse XK space
  float* M = xkf;                 // 32*33 = 1056 floats (transpose buffer)
  float* colred = xkf + 1104;     // 4*16*6 = 384 floats
  const int wv = tid >> 6, lane = tid & 63;
  if ((lane >> 4) == 0) {
#pragma unroll
    for (int e = 0; e < 3; ++e) {
      colred[wv * 96 + tx * 6 + e * 2 + 0] = cs_[e][0];
      colred[wv * 96 + tx * 6 + e * 2 + 1] = cs_[e][1];
    }
  }
  __syncthreads();  // colred ready
  if (tid < 96) {
    int txx = tid / 6, j = tid - txx * 6;
    float v = colred[0 * 96 + txx * 6 + j] + colred[1 * 96 + txx * 6 + j] +
              colred[2 * 96 + txx * 6 + j] + colred[3 * 96 + txx * 6 + j];
    int e = j >> 1, half = j & 1;
    int krow = kt * 32 + txx + half * 16;
    Zp[(((size_t)b * L_ + krow) * 16 + qt) * 3 + e] = v;
  }
  // ---- mirror stores via LDS transpose (coalesced rows); M disjoint from colred
  const int mo = ty * 33 + tx;
  M[mo] = s00; M[mo + 16] = s01;
  M[mo + 16 * 33] = s10; M[mo + 16 * 33 + 16] = s11;
  __syncthreads();
#pragma unroll
  for (int j = 0; j < 4; ++j) {
    int idx = tid + 256 * j, kr = idx >> 5, qc = idx & 31;
    Sb[(kt * 32 + kr) * L_ + qt * 32 + qc] = M[qc * 33 + kr];
  }
  __syncthreads();
  M[mo] = t00; M[mo + 16] = t01;
  M[mo + 16 * 33] = t10; M[mo + 16 * 33 + 16] = t11;
  __syncthreads();
#pragma unroll
  for (int j = 0; j < 4; ++j) {
    int idx = tid + 256 * j, kr = idx >> 5, qc = idx & 31;
    Tb[(kt * 32 + kr) * L_ + qt * 32 + qc] = M[qc * 33 + kr];
  }
}

// ---------------------------------------------------------------------------
// Phase 2 (validated round 7, incl. the strided X2 writeback fix).
// ---------------------------------------------------------------------------
__device__ void phase2_job(int job, const float* __restrict__ x,
                           const float* __restrict__ S, const float* __restrict__ T,
                           const float* __restrict__ Zp, const float* __restrict__ attw,
                           float* __restrict__ X2, SU& u) {
  const int tid = threadIdx.x;
  const int b = job >> 7, q0 = (job & 127) * 4;
  if (tid < 12) {
    int row = tid / 3, j = tid - row * 3;
    const float* zp = Zp + (((size_t)b * L_ + q0 + row) * 16) * 3 + j;
    float z = 0.0f;
#pragma unroll
    for (int t = 0; t < 16; ++t) z += zp[t * 3];
    float winv = frcp(attw[0] + attw[1] + attw[2]);
    u.p2.c[row][j] = attw[j] * winv * frcp(z);
  }
  __syncthreads();
  const float L2E = 1.4426950408889634f, L2E10 = 0.14426950408889634f;
  for (int i = tid; i < 4 * 512; i += 256) {
    int row = i >> 9, kk = i & 511;
    size_t o = ((size_t)b * L_ + q0 + row) * (size_t)L_ + kk;
    float s = S[o], t = T[o];
    float e1 = fexp2(fmaf(s, L2E, -120.0f));
    float e2 = fexp2(fmaf(t, L2E, -32.0f));
    float e3 = fexp2(s * L2E10);
    u.p2.P[row][kk] = u.p2.c[row][0] * e1 + u.p2.c[row][1] * e2 + u.p2.c[row][2] * e3;
  }
  __syncthreads();
  const int d = tid & 127, kh = tid >> 7;
  float a0 = 0, a1 = 0, a2 = 0, a3 = 0;
  if (d < D_) {
    const float* xb = x + ((size_t)b * L_ + kh * 256) * D_;
    for (int g = 0; g < 64; ++g) {
      int kk = kh * 256 + g * 4;
      float4 p0 = *(const float4*)&u.p2.P[0][kk];
      float4 p1 = *(const float4*)&u.p2.P[1][kk];
      float4 p2 = *(const float4*)&u.p2.P[2][kk];
      float4 p3 = *(const float4*)&u.p2.P[3][kk];
      float x0 = xb[(g * 4 + 0) * D_ + d];
      float x1 = xb[(g * 4 + 1) * D_ + d];
      float x2 = xb[(g * 4 + 2) * D_ + d];
      float x3 = xb[(g * 4 + 3) * D_ + d];
      a0 += p0.x * x0 + p0.y * x1 + p0.z * x2 + p0.w * x3;
      a1 += p1.x * x0 + p1.y * x1 + p1.z * x2 + p1.w * x3;
      a2 += p2.x * x0 + p2.y * x1 + p2.z * x2 + p2.w * x3;
      a3 += p3.x * x0 + p3.y * x1 + p3.z * x2 + p3.w * x3;
    }
  }
  __syncthreads();  // P reads done
  u.p2.R[kh][0][d] = a0; u.p2.R[kh][1][d] = a1;
  u.p2.R[kh][2][d] = a2; u.p2.R[kh][3][d] = a3;
  __syncthreads();
  for (int i = tid; i < 4 * D_; i += 256) {
    int row = i / D_, dd = i - row * D_;
    size_t o = ((size_t)b * L_ + q0 + row) * D_ + dd;
    X2[o] = x[o] + u.p2.R[0][row][dd] + u.p2.R[1][row][dd];
  }
}

// ---------------------------------------------------------------------------
// Phase 3 (validated round 7): 128 jobs, 16-wide t-tiles, all 30 channels.
// ---------------------------------------------------------------------------
__device__ void phase3_job(int job, const float* __restrict__ X2,
    const float* __restrict__ w1, const float* __restrict__ b1,
    const float* __restrict__ w2, const float* __restrict__ b2,
    const float* __restrict__ w3, const float* __restrict__ b3,
    float* __restrict__ pooled, SU& u) {
  const int tid = threadIdx.x;
  const int b = job >> 5, tt = job & 31;
  const int t0 = tt * 16;
  const float* xb = X2 + (size_t)b * L_ * D_;
  for (int i = tid; i < 20 * D_; i += 256) {
    int r = i / D_, c = i - r * D_;
    int rg = t0 - 2 + r;
    u.p3.xs[r * 104 + c] = (rg >= 0 && rg < L_) ? xb[(size_t)rg * D_ + c] : 0.0f;
  }
  for (int i = tid; i < 30 * 300; i += 256) {
    int c = i / 300, rest = i - c * 300;
    int h = rest / D_, dd = rest - h * D_;
    int ws = 1 + c / 10;
    int hh = h - (3 - ws);
    float wv = 0.0f;
    if (hh >= 0) {
      if (ws == 1)      wv = w1[c * D_ + dd];
      else if (ws == 2) wv = w2[(c - 10) * 2 * D_ + hh * D_ + dd];
      else              wv = w3[(c - 20) * 3 * D_ + hh * D_ + dd];
    }
    u.p3.wl[c * 304 + h * D_ + dd] = wv;
  }
  __syncthreads();
  const int tl = tid & 15, cgi = tid >> 4;
  const int c0 = cgi, c1 = cgi + 16;
  float vm0 = 0.0f, vm1 = 0.0f;
  const int nrep = (tt == 31) ? 2 : 1;
  for (int rep = 0; rep < nrep; ++rep) {
    int t = t0 + rep * 16 + tl;
    if (t > L_ + 1) continue;
    float acc0 = 0, acc1 = 0;
#pragma unroll
    for (int h = 0; h < 3; ++h) {
      const float4* xr  = (const float4*)&u.p3.xs[(rep * 16 + tl + h) * 104];
      const float4* wr0 = (const float4*)&u.p3.wl[c0 * 304 + h * D_];
      const float4* wr1 = (const float4*)&u.p3.wl[c1 * 304 + h * D_];
#pragma unroll 5
      for (int j = 0; j < 25; ++j) {
        float4 xv = xr[j];
        float4 w0v = wr0[j];
        acc0 += xv.x * w0v.x + xv.y * w0v.y + xv.z * w0v.z + xv.w * w0v.w;
        if (c1 < 30) {
          float4 w1v = wr1[j];
          acc1 += xv.x * w1v.x + xv.y * w1v.y + xv.z * w1v.z + xv.w * w1v.w;
        }
      }
    }
    {
      int wsz = 1 + c0 / 10;
      float bias = (wsz == 1) ? b1[c0] : (wsz == 2 ? b2[c0 - 10] : b3[c0 - 20]);
      if (t < L_ + wsz - 1) vm0 = fmaxf(vm0, fmaxf(acc0 + bias, 0.0f));
    }
    if (c1 < 30) {
      int wsz = 1 + c1 / 10;
      float bias = (wsz == 1) ? b1[c1] : (wsz == 2 ? b2[c1 - 10] : b3[c1 - 20]);
      if (t < L_ + wsz - 1) vm1 = fmaxf(vm1, fmaxf(acc1 + bias, 0.0f));
    }
  }
#pragma unroll
  for (int o = 8; o > 0; o >>= 1) {
    vm0 = fmaxf(vm0, __shfl_xor(vm0, o));
    vm1 = fmaxf(vm1, __shfl_xor(vm1, o));
  }
  if (tl == 0) {
    atomicMax(reinterpret_cast<int*>(&pooled[b * 30 + c0]), __float_as_int(vm0));
    if (c1 < 30)
      atomicMax(reinterpret_cast<int*>(&pooled[b * 30 + c1]), __float_as_int(vm1));
  }
}

__device__ void phase4_linear(float* __restrict__ pooled,
                              const float* __restrict__ lw,
                              const float* __restrict__ lb,
                              float* __restrict__ out) {
  int i = threadIdx.x;
  if (i >= B_ * 2) return;
  int bb = i >> 1, j = i & 1;
  float acc = lb[j];
  int* pI = reinterpret_cast<int*>(pooled);
#pragma unroll
  for (int c = 0; c < 30; ++c) {
    float pv = __int_as_float(atomicMax(&pI[bb * 30 + c], 0));  // coherent read, v>=0
    acc = fmaf(pv, lw[c * 2 + j], acc);
  }
  out[bb * 2 + j] = acc;
}

// ---------------------------------------------------------------------------
// Fused kernel, PLAIN launch: 544 blocks x 256 threads, hand-rolled barriers.
// Counter lifecycle (graph-replay-safe): block 0 zeroes c1/c2/done then
// release-stores ready=MAGIC; all blocks gate barrier-1 on ready==MAGIC;
// the last block through `done` resets all counters to 0 and runs the
// linear head. Counters are left at 0 for the next replay.
// ---------------------------------------------------------------------------
__global__ __launch_bounds__(256, 3) void k_fused(
    const float* __restrict__ x, const float* __restrict__ attw,
    const float* __restrict__ w1, const float* __restrict__ b1,
    const float* __restrict__ w2, const float* __restrict__ b2,
    const float* __restrict__ w3, const float* __restrict__ b3,
    const float* __restrict__ lw, const float* __restrict__ lb,
    float* S, float* T, float* Zp, float* X2, float* pooled, float* out,
    int* bar) {
  __shared__ SU u;
  __shared__ int lastFlag;
  int* ready = bar + 0;
  int* c1    = bar + 1;
  int* c2    = bar + 2;
  int* done  = bar + 3;
  const int bid = blockIdx.x;
  const int tid = threadIdx.x;

  if (bid == 0 && tid == 0) {
    __hip_atomic_store(c1, 0, __ATOMIC_RELAXED, __HIP_MEMORY_SCOPE_AGENT);
    __hip_atomic_store(c2, 0, __ATOMIC_RELAXED, __HIP_MEMORY_SCOPE_AGENT);
    __hip_atomic_store(done, 0, __ATOMIC_RELAXED, __HIP_MEMORY_SCOPE_AGENT);
    __hip_atomic_store(ready, MAGIC_, __ATOMIC_RELEASE, __HIP_MEMORY_SCOPE_AGENT);
  }
  if (bid == 0 && tid < B_ * 30) pooled[tid] = 0.0f;  // flushed by barrier-1 release

  phase1_tile(bid, x, S, T, Zp, u);

  // ---- barrier 1 (gated on ready-flag so counters are known-zero)
  __syncthreads();
  if (tid == 0) {
    while (__hip_atomic_load(ready, __ATOMIC_RELAXED, __HIP_MEMORY_SCOPE_AGENT) != MAGIC_)
      __builtin_amdgcn_s_sleep(4);
    __hip_atomic_fetch_add(c1, 1, __ATOMIC_RELEASE, __HIP_MEMORY_SCOPE_AGENT);
    while (__hip_atomic_load(c1, __ATOMIC_RELAXED, __HIP_MEMORY_SCOPE_AGENT) < NB_)
      __builtin_amdgcn_s_sleep(4);
    (void)__hip_atomic_load(c1, __ATOMIC_ACQUIRE, __HIP_MEMORY_SCOPE_AGENT);
  }
  __syncthreads();

  if (bid < 512) phase2_job(bid, x, S, T, Zp, attw, X2, u);

  grid_barrier(c2);

  if (bid < 128) phase3_job(bid, X2, w1, b1, w2, b2, w3, b3, pooled, u);

  // ---- arrival: last block resets counters and computes the linear head
  __syncthreads();
  if (tid == 0) {
    int old = __hip_atomic_fetch_add(done, 1, __ATOMIC_ACQ_REL, __HIP_MEMORY_SCOPE_AGENT);
    lastFlag = (old == NB_ - 1);
  }
  __syncthreads();
  if (lastFlag) {
    if (tid == 0) {
      __hip_atomic_store(c1, 0, __ATOMIC_RELAXED, __HIP_MEMORY_SCOPE_AGENT);
      __hip_atomic_store(c2, 0, __ATOMIC_RELAXED, __HIP_MEMORY_SCOPE_AGENT);
      __hip_atomic_store(done, 0, __ATOMIC_RELAXED, __HIP_MEMORY_SCOPE_AGENT);
      __hip_atomic_store(ready, 0, __ATOMIC_RELEASE, __HIP_MEMORY_SCOPE_AGENT);
    }
    phase4_linear(pooled, lw, lb, out);
  }
}

extern "C" void kernel_launch(void* const* d_in, const int* in_sizes, int n_in,
                              void* d_out, int out_size, void* d_ws, size_t ws_size,
                              hipStream_t stream) {
  const float* src  = (const float*)d_in[0];
  const float* attw = (const float*)d_in[1];
  const float* w1   = (const float*)d_in[2];
  const float* b1   = (const float*)d_in[3];
  const float* w2   = (const float*)d_in[4];
  const float* b2   = (const float*)d_in[5];
  const float* w3   = (const float*)d_in[6];
  const float* b3   = (const float*)d_in[7];
  const float* lw   = (const float*)d_in[8];
  const float* lb   = (const float*)d_in[9];

  // ws: S | T (1,048,576 f32 each) | Zp (98,304) | X2 (204,800) | pooled(128) | bar(4 ints)
  float* S  = (float*)d_ws;
  float* T  = S + (size_t)B_ * L_ * L_;
  float* Zp = T + (size_t)B_ * L_ * L_;
  float* X2 = Zp + (size_t)B_ * L_ * 16 * 3;
  float* PL = X2 + (size_t)B_ * L_ * D_;
  int* bar  = (int*)(PL + 128);
  float* out = (float*)d_out;

  hipLaunchKernelGGL(k_fused, dim3(NB_), dim3(256), 0, stream,
                     src, attw, w1, b1, w2, b2, w3, b3, lw, lb,
                     S, T, Zp, X2, PL, out, bar);
}

// Round 9
// 102.064 us; speedup vs baseline: 2.4330x; 1.5668x over previous
//
#include <hip/hip_runtime.h>

#define B_ 4
#define L_ 512
#define D_ 100
#define NB_ 544
#define MAGIC_ 0x5ca1ab1e

// bar[] line map (each line = 32 ints = 128 B; only word 0 of a line is used)
#define LN_READY 0    // 17 lines: per-group init-done flags (stay MAGIC across replays)
#define LN_C1G   17   // 17 lines: barrier-1 group counters (target 32)
#define LN_S1    34   // 1 line:   barrier-1 super counter  (target 17)
#define LN_F1    35   // 17 lines: barrier-1 release flags
#define LN_C2G   52   // 16 lines: barrier-2 group counters (target 32)
#define LN_S2    68   // 1 line:   barrier-2 super counter  (target 16)
#define LN_F2    69   // 4 lines:  barrier-2 release flags
#define LN_DG    73   // 4 lines:  done group counters      (target 32)
#define LN_SD    77   // 1 line:   done super counter       (target 4)
#define LN_TOTAL 78

__device__ __forceinline__ float fexp2(float x) { return __builtin_amdgcn_exp2f(x); }
__device__ __forceinline__ float frcp(float x)  { return __builtin_amdgcn_rcpf(x); }

__device__ __forceinline__ int a_load_rlx(int* p) {
  return __hip_atomic_load(p, __ATOMIC_RELAXED, __HIP_MEMORY_SCOPE_AGENT);
}
__device__ __forceinline__ int a_load_acq(int* p) {
  return __hip_atomic_load(p, __ATOMIC_ACQUIRE, __HIP_MEMORY_SCOPE_AGENT);
}
__device__ __forceinline__ void a_store_rlx(int* p, int v) {
  __hip_atomic_store(p, v, __ATOMIC_RELAXED, __HIP_MEMORY_SCOPE_AGENT);
}
__device__ __forceinline__ void a_store_rel(int* p, int v) {
  __hip_atomic_store(p, v, __ATOMIC_RELEASE, __HIP_MEMORY_SCOPE_AGENT);
}
__device__ __forceinline__ int a_add_acqrel(int* p) {
  return __hip_atomic_fetch_add(p, 1, __ATOMIC_ACQ_REL, __HIP_MEMORY_SCOPE_AGENT);
}

// LDS union: max(P1)=52224 B -> 3 blocks/CU (156672 <= 163840) => all 544
// blocks co-resident (544 <= 768); 12 waves/CU, VGPR 68 -> no other cap.
struct P1 { float2 XQ[32 * 102]; float2 XK[32 * 102]; };          // 52224 B
struct P2 { float c[4][3]; float P[4][512]; float R[2][4][128]; }; // 12336 B
struct P3 { float xs[20 * 104]; float wl[30 * 304]; };             // 44800 B
union SU { P1 p1; P2 p2; P3 p3; };

// ---------------------------------------------------------------------------
// Phase 1 (validated round 7/8): one 32x32 upper-tri tile per job.
// ---------------------------------------------------------------------------
__device__ void phase1_tile(int job, const float* __restrict__ x,
                            float* __restrict__ S, float* __restrict__ T,
                            float* __restrict__ Zp, SU& u) {
  int b, qt, kt;
  if (job < 480) {  // off-diagonal tiles: 120 per batch
    b = job / 120;
    int r = job - b * 120;
    qt = 0;
    while (r >= 15 - qt) { r -= 15 - qt; ++qt; }
    kt = qt + 1 + r;
  } else {          // diagonal tiles: 16 per batch
    int dj = job - 480;
    b = dj >> 4;
    qt = kt = dj & 15;
  }
  const bool diag = (kt == qt);
  const int tid = threadIdx.x;
  const float C = 2.8853900817779268f;  // 2*log2(e)
  const float L2E = 1.4426950408889634f;
  const float* xb = x + (size_t)b * L_ * D_;
  for (int i = tid; i < 32 * D_; i += 256) {
    int r = i / D_, c = i - r * D_;
    float xq = xb[(qt * 32 + r) * D_ + c];
    u.p1.XQ[r * 102 + c] = make_float2(xq, fexp2(xq * C));
    if (!diag) {
      float xk = xb[(kt * 32 + r) * D_ + c];
      u.p1.XK[r * 102 + c] = make_float2(xk, fexp2(xk * C));
    }
  }
  __syncthreads();
  const float2* XKp = diag ? u.p1.XQ : u.p1.XK;
  const int tx = tid & 15, ty = tid >> 4;
  float s00 = 0, s01 = 0, s10 = 0, s11 = 0;
  float r00 = 0, r01 = 0, r10 = 0, r11 = 0;
  const float2* qp0 = &u.p1.XQ[ty * 102];
  const float2* qp1 = &u.p1.XQ[(ty + 16) * 102];
  const float2* kp0 = &XKp[tx * 102];
  const float2* kp1 = &XKp[(tx + 16) * 102];
#pragma unroll 2
  for (int d = 0; d < D_; d += 2) {  // 2 d per iter via float4 (b128) reads
    float4 A0 = *(const float4*)&qp0[d];
    float4 A1 = *(const float4*)&qp1[d];
    float4 B0 = *(const float4*)&kp0[d];
    float4 B1 = *(const float4*)&kp1[d];
    s00 += A0.x * B0.x + A0.z * B0.z;
    s01 += A0.x * B1.x + A0.z * B1.z;
    s10 += A1.x * B0.x + A1.z * B0.z;
    s11 += A1.x * B1.x + A1.z * B1.z;
    r00 += frcp(fmaf(A0.y, B0.y, 1.0f)) + frcp(fmaf(A0.w, B0.w, 1.0f));
    r01 += frcp(fmaf(A0.y, B1.y, 1.0f)) + frcp(fmaf(A0.w, B1.w, 1.0f));
    r10 += frcp(fmaf(A1.y, B0.y, 1.0f)) + frcp(fmaf(A1.w, B0.w, 1.0f));
    r11 += frcp(fmaf(A1.y, B1.y, 1.0f)) + frcp(fmaf(A1.w, B1.w, 1.0f));
  }
  float t00 = (float)D_ - 2.0f * r00;
  float t01 = (float)D_ - 2.0f * r01;
  float t10 = (float)D_ - 2.0f * r10;
  float t11 = (float)D_ - 2.0f * r11;
  float e1_00 = fexp2(fmaf(s00, L2E, -120.0f)), e1_01 = fexp2(fmaf(s01, L2E, -120.0f));
  float e1_10 = fexp2(fmaf(s10, L2E, -120.0f)), e1_11 = fexp2(fmaf(s11, L2E, -120.0f));
  float e2_00 = fexp2(fmaf(t00, L2E, -32.0f)),  e2_01 = fexp2(fmaf(t01, L2E, -32.0f));
  float e2_10 = fexp2(fmaf(t10, L2E, -32.0f)),  e2_11 = fexp2(fmaf(t11, L2E, -32.0f));
  const float L2E10 = 0.14426950408889634f;
  float e3_00 = fexp2(s00 * L2E10), e3_01 = fexp2(s01 * L2E10);
  float e3_10 = fexp2(s10 * L2E10), e3_11 = fexp2(s11 * L2E10);

  const int q0r = qt * 32 + ty, q1r = q0r + 16;
  const int k0 = kt * 32 + tx, k1 = k0 + 16;
  float* Sb = S + (size_t)b * L_ * L_;
  float* Tb = T + (size_t)b * L_ * L_;
  Sb[q0r * L_ + k0] = s00; Sb[q0r * L_ + k1] = s01;
  Sb[q1r * L_ + k0] = s10; Sb[q1r * L_ + k1] = s11;
  Tb[q0r * L_ + k0] = t00; Tb[q0r * L_ + k1] = t01;
  Tb[q1r * L_ + k0] = t10; Tb[q1r * L_ + k1] = t11;

  // ---- row Zp partials (reduce e-sums over tx within wave)
  float rs[3][2];
  rs[0][0] = e1_00 + e1_01; rs[0][1] = e1_10 + e1_11;
  rs[1][0] = e2_00 + e2_01; rs[1][1] = e2_10 + e2_11;
  rs[2][0] = e3_00 + e3_01; rs[2][1] = e3_10 + e3_11;
#pragma unroll
  for (int o = 8; o > 0; o >>= 1) {
#pragma unroll
    for (int e = 0; e < 3; ++e) {
      rs[e][0] += __shfl_xor(rs[e][0], o);
      rs[e][1] += __shfl_xor(rs[e][1], o);
    }
  }
  if (tx == 0) {
#pragma unroll
    for (int e = 0; e < 3; ++e) {
      Zp[(((size_t)b * L_ + q0r) * 16 + kt) * 3 + e] = rs[e][0];
      Zp[(((size_t)b * L_ + q1r) * 16 + kt) * 3 + e] = rs[e][1];
    }
  }

  if (diag) return;

  // ---- column Zp partials (mirror rows): shuffles over ty bits then LDS
  float cs_[3][2];
  cs_[0][0] = e1_00 + e1_10; cs_[0][1] = e1_01 + e1_11;
  cs_[1][0] = e2_00 + e2_10; cs_[1][1] = e2_01 + e2_11;
  cs_[2][0] = e3_00 + e3_10; cs_[2][1] = e3_01 + e3_11;
#pragma unroll
  for (int o = 16; o <= 32; o <<= 1) {
#pragma unroll
    for (int e = 0; e < 3; ++e) {
      cs_[e][0] += __shfl_xor(cs_[e][0], o);
      cs_[e][1] += __shfl_xor(cs_[e][1], o);
    }
  }
  __syncthreads();  // all d-loop reads of XK complete before aliasing
  float* xkf = (float*)u.p1.XK;   // reuse XK space
  float* M = xkf;                 // 32*33 = 1056 floats (transpose buffer)
  float* colred = xkf + 1104;     // 4*16*6 = 384 floats
  const int wv = tid >> 6, lane = tid & 63;
  if ((lane >> 4) == 0) {
#pragma unroll
    for (int e = 0; e < 3; ++e) {
      colred[wv * 96 + tx * 6 + e * 2 + 0] = cs_[e][0];
      colred[wv * 96 + tx * 6 + e * 2 + 1] = cs_[e][1];
    }
  }
  __syncthreads();  // colred ready
  if (tid < 96) {
    int txx = tid / 6, j = tid - txx * 6;
    float v = colred[0 * 96 + txx * 6 + j] + colred[1 * 96 + txx * 6 + j] +
              colred[2 * 96 + txx * 6 + j] + colred[3 * 96 + txx * 6 + j];
    int e = j >> 1, half = j & 1;
    int krow = kt * 32 + txx + half * 16;
    Zp[(((size_t)b * L_ + krow) * 16 + qt) * 3 + e] = v;
  }
  // ---- mirror stores via LDS transpose (coalesced rows); M disjoint from colred
  const int mo = ty * 33 + tx;
  M[mo] = s00; M[mo + 16] = s01;
  M[mo + 16 * 33] = s10; M[mo + 16 * 33 + 16] = s11;
  __syncthreads();
#pragma unroll
  for (int j = 0; j < 4; ++j) {
    int idx = tid + 256 * j, kr = idx >> 5, qc = idx & 31;
    Sb[(kt * 32 + kr) * L_ + qt * 32 + qc] = M[qc * 33 + kr];
  }
  __syncthreads();
  M[mo] = t00; M[mo + 16] = t01;
  M[mo + 16 * 33] = t10; M[mo + 16 * 33 + 16] = t11;
  __syncthreads();
#pragma unroll
  for (int j = 0; j < 4; ++j) {
    int idx = tid + 256 * j, kr = idx >> 5, qc = idx & 31;
    Tb[(kt * 32 + kr) * L_ + qt * 32 + qc] = M[qc * 33 + kr];
  }
}

// ---------------------------------------------------------------------------
// Phase 2 (validated round 7/8, incl. the strided X2 writeback fix).
// ---------------------------------------------------------------------------
__device__ void phase2_job(int job, const float* __restrict__ x,
                           const float* __restrict__ S, const float* __restrict__ T,
                           const float* __restrict__ Zp, const float* __restrict__ attw,
                           float* __restrict__ X2, SU& u) {
  const int tid = threadIdx.x;
  const int b = job >> 7, q0 = (job & 127) * 4;
  if (tid < 12) {
    int row = tid / 3, j = tid - row * 3;
    const float* zp = Zp + (((size_t)b * L_ + q0 + row) * 16) * 3 + j;
    float z = 0.0f;
#pragma unroll
    for (int t = 0; t < 16; ++t) z += zp[t * 3];
    float winv = frcp(attw[0] + attw[1] + attw[2]);
    u.p2.c[row][j] = attw[j] * winv * frcp(z);
  }
  __syncthreads();
  const float L2E = 1.4426950408889634f, L2E10 = 0.14426950408889634f;
  for (int i = tid; i < 4 * 512; i += 256) {
    int row = i >> 9, kk = i & 511;
    size_t o = ((size_t)b * L_ + q0 + row) * (size_t)L_ + kk;
    float s = S[o], t = T[o];
    float e1 = fexp2(fmaf(s, L2E, -120.0f));
    float e2 = fexp2(fmaf(t, L2E, -32.0f));
    float e3 = fexp2(s * L2E10);
    u.p2.P[row][kk] = u.p2.c[row][0] * e1 + u.p2.c[row][1] * e2 + u.p2.c[row][2] * e3;
  }
  __syncthreads();
  const int d = tid & 127, kh = tid >> 7;
  float a0 = 0, a1 = 0, a2 = 0, a3 = 0;
  if (d < D_) {
    const float* xb = x + ((size_t)b * L_ + kh * 256) * D_;
    for (int g = 0; g < 64; ++g) {
      int kk = kh * 256 + g * 4;
      float4 p0 = *(const float4*)&u.p2.P[0][kk];
      float4 p1 = *(const float4*)&u.p2.P[1][kk];
      float4 p2 = *(const float4*)&u.p2.P[2][kk];
      float4 p3 = *(const float4*)&u.p2.P[3][kk];
      float x0 = xb[(g * 4 + 0) * D_ + d];
      float x1 = xb[(g * 4 + 1) * D_ + d];
      float x2 = xb[(g * 4 + 2) * D_ + d];
      float x3 = xb[(g * 4 + 3) * D_ + d];
      a0 += p0.x * x0 + p0.y * x1 + p0.z * x2 + p0.w * x3;
      a1 += p1.x * x0 + p1.y * x1 + p1.z * x2 + p1.w * x3;
      a2 += p2.x * x0 + p2.y * x1 + p2.z * x2 + p2.w * x3;
      a3 += p3.x * x0 + p3.y * x1 + p3.z * x2 + p3.w * x3;
    }
  }
  __syncthreads();  // P reads done
  u.p2.R[kh][0][d] = a0; u.p2.R[kh][1][d] = a1;
  u.p2.R[kh][2][d] = a2; u.p2.R[kh][3][d] = a3;
  __syncthreads();
  for (int i = tid; i < 4 * D_; i += 256) {
    int row = i / D_, dd = i - row * D_;
    size_t o = ((size_t)b * L_ + q0 + row) * D_ + dd;
    X2[o] = x[o] + u.p2.R[0][row][dd] + u.p2.R[1][row][dd];
  }
}

// ---------------------------------------------------------------------------
// Phase 3 (validated round 7/8): 128 jobs, 16-wide t-tiles, all 30 channels.
// ---------------------------------------------------------------------------
__device__ void phase3_job(int job, const float* __restrict__ X2,
    const float* __restrict__ w1, const float* __restrict__ b1,
    const float* __restrict__ w2, const float* __restrict__ b2,
    const float* __restrict__ w3, const float* __restrict__ b3,
    float* __restrict__ pooled, SU& u) {
  const int tid = threadIdx.x;
  const int b = job >> 5, tt = job & 31;
  const int t0 = tt * 16;
  const float* xb = X2 + (size_t)b * L_ * D_;
  for (int i = tid; i < 20 * D_; i += 256) {
    int r = i / D_, c = i - r * D_;
    int rg = t0 - 2 + r;
    u.p3.xs[r * 104 + c] = (rg >= 0 && rg < L_) ? xb[(size_t)rg * D_ + c] : 0.0f;
  }
  for (int i = tid; i < 30 * 300; i += 256) {
    int c = i / 300, rest = i - c * 300;
    int h = rest / D_, dd = rest - h * D_;
    int ws = 1 + c / 10;
    int hh = h - (3 - ws);
    float wv = 0.0f;
    if (hh >= 0) {
      if (ws == 1)      wv = w1[c * D_ + dd];
      else if (ws == 2) wv = w2[(c - 10) * 2 * D_ + hh * D_ + dd];
      else              wv = w3[(c - 20) * 3 * D_ + hh * D_ + dd];
    }
    u.p3.wl[c * 304 + h * D_ + dd] = wv;
  }
  __syncthreads();
  const int tl = tid & 15, cgi = tid >> 4;
  const int c0 = cgi, c1 = cgi + 16;
  float vm0 = 0.0f, vm1 = 0.0f;
  const int nrep = (tt == 31) ? 2 : 1;
  for (int rep = 0; rep < nrep; ++rep) {
    int t = t0 + rep * 16 + tl;
    if (t > L_ + 1) continue;
    float acc0 = 0, acc1 = 0;
#pragma unroll
    for (int h = 0; h < 3; ++h) {
      const float4* xr  = (const float4*)&u.p3.xs[(rep * 16 + tl + h) * 104];
      const float4* wr0 = (const float4*)&u.p3.wl[c0 * 304 + h * D_];
      const float4* wr1 = (const float4*)&u.p3.wl[c1 * 304 + h * D_];
#pragma unroll 5
      for (int j = 0; j < 25; ++j) {
        float4 xv = xr[j];
        float4 w0v = wr0[j];
        acc0 += xv.x * w0v.x + xv.y * w0v.y + xv.z * w0v.z + xv.w * w0v.w;
        if (c1 < 30) {
          float4 w1v = wr1[j];
          acc1 += xv.x * w1v.x + xv.y * w1v.y + xv.z * w1v.z + xv.w * w1v.w;
        }
      }
    }
    {
      int wsz = 1 + c0 / 10;
      float bias = (wsz == 1) ? b1[c0] : (wsz == 2 ? b2[c0 - 10] : b3[c0 - 20]);
      if (t < L_ + wsz - 1) vm0 = fmaxf(vm0, fmaxf(acc0 + bias, 0.0f));
    }
    if (c1 < 30) {
      int wsz = 1 + c1 / 10;
      float bias = (wsz == 1) ? b1[c1] : (wsz == 2 ? b2[c1 - 10] : b3[c1 - 20]);
      if (t < L_ + wsz - 1) vm1 = fmaxf(vm1, fmaxf(acc1 + bias, 0.0f));
    }
  }
#pragma unroll
  for (int o = 8; o > 0; o >>= 1) {
    vm0 = fmaxf(vm0, __shfl_xor(vm0, o));
    vm1 = fmaxf(vm1, __shfl_xor(vm1, o));
  }
  if (tl == 0) {
    atomicMax(reinterpret_cast<int*>(&pooled[b * 30 + c0]), __float_as_int(vm0));
    if (c1 < 30)
      atomicMax(reinterpret_cast<int*>(&pooled[b * 30 + c1]), __float_as_int(vm1));
  }
}

__device__ void phase4_linear(float* __restrict__ pooled,
                              const float* __restrict__ lw,
                              const float* __restrict__ lb,
                              float* __restrict__ out) {
  int i = threadIdx.x;
  if (i >= B_ * 2) return;
  int bb = i >> 1, j = i & 1;
  float acc = lb[j];
  int* pI = reinterpret_cast<int*>(pooled);
#pragma unroll
  for (int c = 0; c < 30; ++c) {
    float pv = __int_as_float(atomicMax(&pI[bb * 30 + c], 0));  // coherent read, v>=0
    acc = fmaf(pv, lw[c * 2 + j], acc);
  }
  out[bb * 2 + j] = acc;
}

// ---------------------------------------------------------------------------
// Fused kernel, plain launch, hierarchical barriers:
//   arrive: fetch_add on own group line (32/group) -> group-last adds super
//           -> super-last fans out per-group release flags.
//   wait:   poll own group's flag line only (32 pollers/line).
// Participants trimmed: bid>=512 exit after c1 arrive; bid in [128,512) exit
// after c2 arrive; done counts only the 128 phase-3 blocks.
// Init gate runs ONCE: ready[g] lines persist as MAGIC across graph replays;
// the done-last block resets only counter/flag lines (17..77) to 0.
// ---------------------------------------------------------------------------
__global__ __launch_bounds__(256, 3) void k_fused(
    const float* __restrict__ x, const float* __restrict__ attw,
    const float* __restrict__ w1, const float* __restrict__ b1,
    const float* __restrict__ w2, const float* __restrict__ b2,
    const float* __restrict__ w3, const float* __restrict__ b3,
    const float* __restrict__ lw, const float* __restrict__ lb,
    float* S, float* T, float* Zp, float* X2, float* pooled, float* out,
    int* bar) {
  __shared__ SU u;
  __shared__ int lastFlag;
  const int bid = blockIdx.x;
  const int tid = threadIdx.x;
  const int g = bid >> 5;

  if (bid == 0 && tid == 0) {
    if (a_load_rlx(&bar[32 * LN_READY]) != MAGIC_) {   // first launch only
      for (int ln = LN_C1G; ln < LN_TOTAL; ++ln) a_store_rlx(&bar[32 * ln], 0);
      for (int ln = 0; ln < 17; ++ln) a_store_rel(&bar[32 * (LN_READY + ln)], MAGIC_);
    }
  }
  if (bid == 0 && tid < B_ * 30) pooled[tid] = 0.0f;  // published by c1 release

  phase1_tile(bid, x, S, T, Zp, u);

  // ---- barrier 1 arrive (all 544), gated on own ready line
  __syncthreads();
  if (tid == 0) {
    while (a_load_rlx(&bar[32 * (LN_READY + g)]) != MAGIC_) __builtin_amdgcn_s_sleep(8);
    (void)a_load_acq(&bar[32 * (LN_READY + g)]);
    int old = a_add_acqrel(&bar[32 * (LN_C1G + g)]);
    if (old == 31) {
      int so = a_add_acqrel(&bar[32 * LN_S1]);
      if (so == 16) {
        for (int f = 0; f < 17; ++f) a_store_rel(&bar[32 * (LN_F1 + f)], 1);
      }
    }
  }
  if (bid >= 512) return;  // diag producers: no downstream work

  // ---- barrier 1 wait (512 blocks, 32 per flag line)
  if (tid == 0) {
    while (a_load_rlx(&bar[32 * (LN_F1 + g)]) == 0) __builtin_amdgcn_s_sleep(2);
    (void)a_load_acq(&bar[32 * (LN_F1 + g)]);
  }
  __syncthreads();

  phase2_job(bid, x, S, T, Zp, attw, X2, u);

  // ---- barrier 2 arrive (512)
  __syncthreads();
  if (tid == 0) {
    int old = a_add_acqrel(&bar[32 * (LN_C2G + g)]);
    if (old == 31) {
      int so = a_add_acqrel(&bar[32 * LN_S2]);
      if (so == 15) {
        for (int f = 0; f < 4; ++f) a_store_rel(&bar[32 * (LN_F2 + f)], 1);
      }
    }
  }
  if (bid >= 128) return;  // phase-2-only blocks exit

  // ---- barrier 2 wait (128 blocks, 32 per flag line)
  if (tid == 0) {
    while (a_load_rlx(&bar[32 * (LN_F2 + g)]) == 0) __builtin_amdgcn_s_sleep(2);
    (void)a_load_acq(&bar[32 * (LN_F2 + g)]);
  }
  __syncthreads();

  phase3_job(bid, X2, w1, b1, w2, b2, w3, b3, pooled, u);

  // ---- done (128 blocks): hierarchical; super-last resets + linear head
  __syncthreads();
  if (tid == 0) {
    int isLast = 0;
    int old = a_add_acqrel(&bar[32 * (LN_DG + g)]);
    if (old == 31) {
      int so = a_add_acqrel(&bar[32 * LN_SD]);
      if (so == 3) isLast = 1;
    }
    lastFlag = isLast;
  }
  __syncthreads();
  if (lastFlag) {
    if (tid == 0) {
      for (int ln = LN_C1G; ln < LN_TOTAL; ++ln) a_store_rlx(&bar[32 * ln], 0);
      // ready lines stay MAGIC -> steady-state replays skip the init gate
    }
    phase4_linear(pooled, lw, lb, out);
  }
}

extern "C" void kernel_launch(void* const* d_in, const int* in_sizes, int n_in,
                              void* d_out, int out_size, void* d_ws, size_t ws_size,
                              hipStream_t stream) {
  const float* src  = (const float*)d_in[0];
  const float* attw = (const float*)d_in[1];
  const float* w1   = (const float*)d_in[2];
  const float* b1   = (const float*)d_in[3];
  const float* w2   = (const float*)d_in[4];
  const float* b2   = (const float*)d_in[5];
  const float* w3   = (const float*)d_in[6];
  const float* b3   = (const float*)d_in[7];
  const float* lw   = (const float*)d_in[8];
  const float* lb   = (const float*)d_in[9];

  // ws: S | T (1,048,576 f32 each) | Zp (98,304) | X2 (204,800) | pooled(128)
  //     | bar (78 lines x 32 ints, 128B-padded)
  float* S  = (float*)d_ws;
  float* T  = S + (size_t)B_ * L_ * L_;
  float* Zp = T + (size_t)B_ * L_ * L_;
  float* X2 = Zp + (size_t)B_ * L_ * 16 * 3;
  float* PL = X2 + (size_t)B_ * L_ * D_;
  int* bar  = (int*)(PL + 128);
  float* out = (float*)d_out;

  hipLaunchKernelGGL(k_fused, dim3(NB_), dim3(256), 0, stream,
                     src, attw, w1, b1, w2, b2, w3, b3, lw, lb,
                     S, T, Zp, X2, PL, out, bar);
}

// Round 10
// 68.890 us; speedup vs baseline: 3.6047x; 1.4816x over previous
//
#include <hip/hip_runtime.h>

#define B_ 4
#define L_ 512
#define D_ 100

__device__ __forceinline__ float fexp2(float x) { return __builtin_amdgcn_exp2f(x); }
__device__ __forceinline__ float frcp(float x)  { return __builtin_amdgcn_rcpf(x); }

// ---------------------------------------------------------------------------
// K1: scores (device-validated rounds 7-9, verbatim phase-1 logic).
// One 32x32 upper-tri tile per block (544 = (120 off-diag + 16 diag) x 4).
// Writes S,T (direct + mirror via LDS transpose) and Zp row/col partial sums
// of e1=exp2(s*L2E-120), e2=exp2(t*L2E-32), e3=exp2(s*L2E/10).
// Block 0 inits pooled + arrival counter for K2 (round-3-proven lifecycle).
// ---------------------------------------------------------------------------
__global__ __launch_bounds__(256) void k1_scores(const float* __restrict__ x,
                                                 float* __restrict__ S,
                                                 float* __restrict__ T,
                                                 float* __restrict__ Zp,
                                                 int* __restrict__ counter,
                                                 float* __restrict__ pooled) {
  __shared__ float2 XQ[32 * 102];
  __shared__ float2 XK[32 * 102];
  const int tid = threadIdx.x;
  const int job = blockIdx.x;
  if (job == 0) {
    if (tid < B_ * 30) pooled[tid] = 0.0f;
    if (tid == 128) *counter = 0;
  }
  int b, qt, kt;
  if (job < 480) {  // off-diagonal tiles: 120 per batch
    b = job / 120;
    int r = job - b * 120;
    qt = 0;
    while (r >= 15 - qt) { r -= 15 - qt; ++qt; }
    kt = qt + 1 + r;
  } else {          // diagonal tiles: 16 per batch
    int dj = job - 480;
    b = dj >> 4;
    qt = kt = dj & 15;
  }
  const bool diag = (kt == qt);
  const float C = 2.8853900817779268f;  // 2*log2(e)
  const float L2E = 1.4426950408889634f;
  const float* xb = x + (size_t)b * L_ * D_;
  for (int i = tid; i < 32 * D_; i += 256) {
    int r = i / D_, c = i - r * D_;
    float xq = xb[(qt * 32 + r) * D_ + c];
    XQ[r * 102 + c] = make_float2(xq, fexp2(xq * C));
    if (!diag) {
      float xk = xb[(kt * 32 + r) * D_ + c];
      XK[r * 102 + c] = make_float2(xk, fexp2(xk * C));
    }
  }
  __syncthreads();
  const float2* XKp = diag ? XQ : XK;
  const int tx = tid & 15, ty = tid >> 4;
  float s00 = 0, s01 = 0, s10 = 0, s11 = 0;
  float r00 = 0, r01 = 0, r10 = 0, r11 = 0;
  const float2* qp0 = &XQ[ty * 102];
  const float2* qp1 = &XQ[(ty + 16) * 102];
  const float2* kp0 = &XKp[tx * 102];
  const float2* kp1 = &XKp[(tx + 16) * 102];
#pragma unroll 2
  for (int d = 0; d < D_; d += 2) {  // 2 d per iter via float4 (b128) reads
    float4 A0 = *(const float4*)&qp0[d];
    float4 A1 = *(const float4*)&qp1[d];
    float4 B0 = *(const float4*)&kp0[d];
    float4 B1 = *(const float4*)&kp1[d];
    s00 += A0.x * B0.x + A0.z * B0.z;
    s01 += A0.x * B1.x + A0.z * B1.z;
    s10 += A1.x * B0.x + A1.z * B0.z;
    s11 += A1.x * B1.x + A1.z * B1.z;
    r00 += frcp(fmaf(A0.y, B0.y, 1.0f)) + frcp(fmaf(A0.w, B0.w, 1.0f));
    r01 += frcp(fmaf(A0.y, B1.y, 1.0f)) + frcp(fmaf(A0.w, B1.w, 1.0f));
    r10 += frcp(fmaf(A1.y, B0.y, 1.0f)) + frcp(fmaf(A1.w, B0.w, 1.0f));
    r11 += frcp(fmaf(A1.y, B1.y, 1.0f)) + frcp(fmaf(A1.w, B1.w, 1.0f));
  }
  float t00 = (float)D_ - 2.0f * r00;
  float t01 = (float)D_ - 2.0f * r01;
  float t10 = (float)D_ - 2.0f * r10;
  float t11 = (float)D_ - 2.0f * r11;
  float e1_00 = fexp2(fmaf(s00, L2E, -120.0f)), e1_01 = fexp2(fmaf(s01, L2E, -120.0f));
  float e1_10 = fexp2(fmaf(s10, L2E, -120.0f)), e1_11 = fexp2(fmaf(s11, L2E, -120.0f));
  float e2_00 = fexp2(fmaf(t00, L2E, -32.0f)),  e2_01 = fexp2(fmaf(t01, L2E, -32.0f));
  float e2_10 = fexp2(fmaf(t10, L2E, -32.0f)),  e2_11 = fexp2(fmaf(t11, L2E, -32.0f));
  const float L2E10 = 0.14426950408889634f;
  float e3_00 = fexp2(s00 * L2E10), e3_01 = fexp2(s01 * L2E10);
  float e3_10 = fexp2(s10 * L2E10), e3_11 = fexp2(s11 * L2E10);

  const int q0r = qt * 32 + ty, q1r = q0r + 16;
  const int k0 = kt * 32 + tx, k1 = k0 + 16;
  float* Sb = S + (size_t)b * L_ * L_;
  float* Tb = T + (size_t)b * L_ * L_;
  Sb[q0r * L_ + k0] = s00; Sb[q0r * L_ + k1] = s01;
  Sb[q1r * L_ + k0] = s10; Sb[q1r * L_ + k1] = s11;
  Tb[q0r * L_ + k0] = t00; Tb[q0r * L_ + k1] = t01;
  Tb[q1r * L_ + k0] = t10; Tb[q1r * L_ + k1] = t11;

  // ---- row Zp partials (reduce e-sums over tx within wave)
  float rs[3][2];
  rs[0][0] = e1_00 + e1_01; rs[0][1] = e1_10 + e1_11;
  rs[1][0] = e2_00 + e2_01; rs[1][1] = e2_10 + e2_11;
  rs[2][0] = e3_00 + e3_01; rs[2][1] = e3_10 + e3_11;
#pragma unroll
  for (int o = 8; o > 0; o >>= 1) {
#pragma unroll
    for (int e = 0; e < 3; ++e) {
      rs[e][0] += __shfl_xor(rs[e][0], o);
      rs[e][1] += __shfl_xor(rs[e][1], o);
    }
  }
  if (tx == 0) {
#pragma unroll
    for (int e = 0; e < 3; ++e) {
      Zp[(((size_t)b * L_ + q0r) * 16 + kt) * 3 + e] = rs[e][0];
      Zp[(((size_t)b * L_ + q1r) * 16 + kt) * 3 + e] = rs[e][1];
    }
  }

  if (diag) return;

  // ---- column Zp partials (mirror rows): shuffles over ty bits then LDS
  float cs_[3][2];
  cs_[0][0] = e1_00 + e1_10; cs_[0][1] = e1_01 + e1_11;
  cs_[1][0] = e2_00 + e2_10; cs_[1][1] = e2_01 + e2_11;
  cs_[2][0] = e3_00 + e3_10; cs_[2][1] = e3_01 + e3_11;
#pragma unroll
  for (int o = 16; o <= 32; o <<= 1) {
#pragma unroll
    for (int e = 0; e < 3; ++e) {
      cs_[e][0] += __shfl_xor(cs_[e][0], o);
      cs_[e][1] += __shfl_xor(cs_[e][1], o);
    }
  }
  __syncthreads();  // all d-loop reads of XK complete before aliasing
  float* xkf = (float*)XK;        // reuse XK space
  float* M = xkf;                 // 32*33 = 1056 floats (transpose buffer)
  float* colred = xkf + 1104;     // 4*16*6 = 384 floats
  const int wv = tid >> 6, lane = tid & 63;
  if ((lane >> 4) == 0) {
#pragma unroll
    for (int e = 0; e < 3; ++e) {
      colred[wv * 96 + tx * 6 + e * 2 + 0] = cs_[e][0];
      colred[wv * 96 + tx * 6 + e * 2 + 1] = cs_[e][1];
    }
  }
  __syncthreads();  // colred ready
  if (tid < 96) {
    int txx = tid / 6, j = tid - txx * 6;
    float v = colred[0 * 96 + txx * 6 + j] + colred[1 * 96 + txx * 6 + j] +
              colred[2 * 96 + txx * 6 + j] + colred[3 * 96 + txx * 6 + j];
    int e = j >> 1, half = j & 1;
    int krow = kt * 32 + txx + half * 16;
    Zp[(((size_t)b * L_ + krow) * 16 + qt) * 3 + e] = v;
  }
  // ---- mirror stores via LDS transpose (coalesced rows); M disjoint from colred
  const int mo = ty * 33 + tx;
  M[mo] = s00; M[mo + 16] = s01;
  M[mo + 16 * 33] = s10; M[mo + 16 * 33 + 16] = s11;
  __syncthreads();
#pragma unroll
  for (int j = 0; j < 4; ++j) {
    int idx = tid + 256 * j, kr = idx >> 5, qc = idx & 31;
    Sb[(kt * 32 + kr) * L_ + qt * 32 + qc] = M[qc * 33 + kr];
  }
  __syncthreads();
  M[mo] = t00; M[mo + 16] = t01;
  M[mo + 16 * 33] = t10; M[mo + 16 * 33 + 16] = t11;
  __syncthreads();
#pragma unroll
  for (int j = 0; j < 4; ++j) {
    int idx = tid + 256 * j, kr = idx >> 5, qc = idx & 31;
    Tb[(kt * 32 + kr) * L_ + qt * 32 + qc] = M[qc * 33 + kr];
  }
}

// ---------------------------------------------------------------------------
// K2: fused normalize + PV + residual + conv + maxpool + linear.
// 512 blocks; block (b = bid>>7, q0 = (bid&127)*4) owns conv outputs
// t = q0+2..q0+5 (block q0=0 also does t=0,1; q0=508 covers tails 512,513).
// It computes the 6 PV rows q0..q0+5 it needs LOCALLY (2-row forward halo,
// +50% PV work, ~0.8us) -> X2 lives only in LDS; no global X2, no barrier.
// Rows >= 512 are zero (conv zero-padding). Linear head via arrival counter
// (round-3-proven pattern, target 512).
// ---------------------------------------------------------------------------
__global__ __launch_bounds__(256) void k2_fused(const float* __restrict__ x,
    const float* __restrict__ S, const float* __restrict__ T,
    const float* __restrict__ Zp, const float* __restrict__ attw,
    const float* __restrict__ w1, const float* __restrict__ b1,
    const float* __restrict__ w2, const float* __restrict__ b2,
    const float* __restrict__ w3, const float* __restrict__ b3,
    const float* __restrict__ lw, const float* __restrict__ lb,
    float* __restrict__ pooled, int* __restrict__ counter,
    float* __restrict__ out) {
  __shared__ float wl[30 * 304];      // zero-padded right-aligned ws=3 weights
  __shared__ float cc[6][3];
  __shared__ float P[6][512];
  __shared__ float R[2][6][128];
  __shared__ float X2L[6][104];
  __shared__ int lastFlag;
  const int tid = threadIdx.x;
  const int b = blockIdx.x >> 7, q0 = (blockIdx.x & 127) * 4;
  const float L2E = 1.4426950408889634f, L2E10 = 0.14426950408889634f;

  // ---- stage conv weights (same mapping as validated phase3)
  for (int i = tid; i < 30 * 300; i += 256) {
    int c = i / 300, rest = i - c * 300;
    int h = rest / D_, dd = rest - h * D_;
    int ws = 1 + c / 10;
    int hh = h - (3 - ws);
    float wv = 0.0f;
    if (hh >= 0) {
      if (ws == 1)      wv = w1[c * D_ + dd];
      else if (ws == 2) wv = w2[(c - 10) * 2 * D_ + hh * D_ + dd];
      else              wv = w3[(c - 20) * 3 * D_ + hh * D_ + dd];
    }
    wl[c * 304 + h * D_ + dd] = wv;
  }
  // ---- softmax coefficients for 6 rows (rows >= L get c=0)
  if (tid < 18) {
    int row = tid / 3, j = tid - row * 3;
    int qr = q0 + row;
    float cv = 0.0f;
    if (qr < L_) {
      const float* zp = Zp + ((size_t)b * L_ + qr) * 16 * 3 + j;
      float z = 0.0f;
#pragma unroll
      for (int t = 0; t < 16; ++t) z += zp[t * 3];
      float winv = frcp(attw[0] + attw[1] + attw[2]);
      cv = attw[j] * winv * frcp(z);
    }
    cc[row][j] = cv;
  }
  __syncthreads();

  // ---- P-form: 6 rows x 512 k (bit-identical exps to K1's Zp path)
  for (int i = tid; i < 6 * 512; i += 256) {
    int row = i >> 9, kk = i & 511;
    int qr = q0 + row;
    float pv = 0.0f;
    if (qr < L_) {
      size_t o = ((size_t)b * L_ + qr) * (size_t)L_ + kk;
      float s = S[o], t = T[o];
      pv = cc[row][0] * fexp2(fmaf(s, L2E, -120.0f)) +
           cc[row][1] * fexp2(fmaf(t, L2E, -32.0f)) +
           cc[row][2] * fexp2(s * L2E10);
    }
    P[row][kk] = pv;
  }
  __syncthreads();

  // ---- PV: thread (d<128, kh<2), 6 row-accumulators (validated k_pv pattern)
  const int d = tid & 127, kh = tid >> 7;
  float a0 = 0, a1 = 0, a2 = 0, a3 = 0, a4 = 0, a5 = 0;
  if (d < D_) {
    const float* xb = x + ((size_t)b * L_ + kh * 256) * D_;
    for (int g = 0; g < 64; ++g) {
      int kk = kh * 256 + g * 4;
      float x0 = xb[(g * 4 + 0) * D_ + d];
      float x1 = xb[(g * 4 + 1) * D_ + d];
      float x2 = xb[(g * 4 + 2) * D_ + d];
      float x3 = xb[(g * 4 + 3) * D_ + d];
      float4 p;
      p = *(const float4*)&P[0][kk]; a0 += p.x*x0 + p.y*x1 + p.z*x2 + p.w*x3;
      p = *(const float4*)&P[1][kk]; a1 += p.x*x0 + p.y*x1 + p.z*x2 + p.w*x3;
      p = *(const float4*)&P[2][kk]; a2 += p.x*x0 + p.y*x1 + p.z*x2 + p.w*x3;
      p = *(const float4*)&P[3][kk]; a3 += p.x*x0 + p.y*x1 + p.z*x2 + p.w*x3;
      p = *(const float4*)&P[4][kk]; a4 += p.x*x0 + p.y*x1 + p.z*x2 + p.w*x3;
      p = *(const float4*)&P[5][kk]; a5 += p.x*x0 + p.y*x1 + p.z*x2 + p.w*x3;
    }
  }
  R[kh][0][d] = a0; R[kh][1][d] = a1; R[kh][2][d] = a2;
  R[kh][3][d] = a3; R[kh][4][d] = a4; R[kh][5][d] = a5;
  __syncthreads();

  // ---- X2 (LDS only): src + attn for rows q0..q0+5; zero for rows >= L
  for (int i = tid; i < 6 * D_; i += 256) {
    int r = i / D_, dd = i - r * D_;
    int qr = q0 + r;
    float v = 0.0f;
    if (qr < L_)
      v = x[((size_t)b * L_ + qr) * D_ + dd] + R[0][r][dd] + R[1][r][dd];
    X2L[r][dd] = v;
  }
  __syncthreads();

  // ---- conv + ReLU + max: thread (c = tid>>3 < 30, tl = tid&7)
  const int c = tid >> 3, tl = tid & 7;
  float vm = 0.0f;
  if (c < 30) {
    int t = -1;
    if (tl < 4) t = q0 + 2 + tl;
    else if (q0 == 0 && tl < 6) t = tl - 4;   // block 0 extras: t = 0, 1
    int wsz = 1 + c / 10;
    if (t >= 0 && t < L_ + wsz - 1) {
      float acc = 0.0f;
#pragma unroll
      for (int h = 0; h < 3; ++h) {
        int idx = t - 2 + h - q0;             // row index into X2L (<= 5)
        if (idx >= 0) {
          const float4* xr = (const float4*)&X2L[idx][0];
          const float4* wr = (const float4*)&wl[c * 304 + h * D_];
#pragma unroll 5
          for (int j = 0; j < 25; ++j) {
            float4 xv = xr[j], wv = wr[j];
            acc += xv.x * wv.x + xv.y * wv.y + xv.z * wv.z + xv.w * wv.w;
          }
        }
      }
      float bias = (wsz == 1) ? b1[c] : (wsz == 2 ? b2[c - 10] : b3[c - 20]);
      vm = fmaxf(acc + bias, 0.0f);
    }
  }
  vm = fmaxf(vm, __shfl_xor(vm, 1));
  vm = fmaxf(vm, __shfl_xor(vm, 2));
  vm = fmaxf(vm, __shfl_xor(vm, 4));
  if (c < 30 && tl == 0)
    atomicMax(reinterpret_cast<int*>(&pooled[b * 30 + c]), __float_as_int(vm));

  // ---- arrival counter: last of 512 blocks computes the linear head
  __syncthreads();
  if (tid == 0) {
    __threadfence();
    int old = atomicAdd(counter, 1);
    lastFlag = (old == 512 - 1);
  }
  __syncthreads();
  if (lastFlag && tid < B_ * 2) {
    int bb = tid >> 1, j = tid & 1;
    float acc = lb[j];
    int* pI = reinterpret_cast<int*>(pooled);
#pragma unroll
    for (int cch = 0; cch < 30; ++cch) {
      int pi = atomicMax(&pI[bb * 30 + cch], 0);  // coherent read (values >= 0)
      acc = fmaf(__int_as_float(pi), lw[cch * 2 + j], acc);
    }
    out[bb * 2 + j] = acc;
  }
}

extern "C" void kernel_launch(void* const* d_in, const int* in_sizes, int n_in,
                              void* d_out, int out_size, void* d_ws, size_t ws_size,
                              hipStream_t stream) {
  const float* src  = (const float*)d_in[0];
  const float* attw = (const float*)d_in[1];
  const float* w1   = (const float*)d_in[2];
  const float* b1   = (const float*)d_in[3];
  const float* w2   = (const float*)d_in[4];
  const float* b2   = (const float*)d_in[5];
  const float* w3   = (const float*)d_in[6];
  const float* b3   = (const float*)d_in[7];
  const float* lw   = (const float*)d_in[8];
  const float* lb   = (const float*)d_in[9];

  // ws: S | T (1,048,576 f32 each) | Zp (98,304) | pooled(128) | counter
  float* S  = (float*)d_ws;
  float* T  = S + (size_t)B_ * L_ * L_;
  float* Zp = T + (size_t)B_ * L_ * L_;
  float* PL = Zp + (size_t)B_ * L_ * 16 * 3;
  int* counter = (int*)(PL + 128);
  float* out = (float*)d_out;

  hipLaunchKernelGGL(k1_scores, dim3(544), dim3(256), 0, stream,
                     src, S, T, Zp, counter, PL);
  hipLaunchKernelGGL(k2_fused, dim3(512), dim3(256), 0, stream,
                     src, S, T, Zp, attw, w1, b1, w2, b2, w3, b3, lw, lb,
                     PL, counter, out);
}

// Round 11
// 62.710 us; speedup vs baseline: 3.9599x; 1.0985x over previous
//
#include <hip/hip_runtime.h>

#define B_ 4
#define L_ 512
#define D_ 100

__device__ __forceinline__ float fexp2(float x) { return __builtin_amdgcn_exp2f(x); }
__device__ __forceinline__ float frcp(float x)  { return __builtin_amdgcn_rcpf(x); }

// ---------------------------------------------------------------------------
// K1: scores (device-validated rounds 7-10, VERBATIM).
// ---------------------------------------------------------------------------
__global__ __launch_bounds__(256) void k1_scores(const float* __restrict__ x,
                                                 float* __restrict__ S,
                                                 float* __restrict__ T,
                                                 float* __restrict__ Zp,
                                                 int* __restrict__ counter,
                                                 float* __restrict__ pooled) {
  __shared__ float2 XQ[32 * 102];
  __shared__ float2 XK[32 * 102];
  const int tid = threadIdx.x;
  const int job = blockIdx.x;
  if (job == 0) {
    if (tid < B_ * 30) pooled[tid] = 0.0f;
    if (tid == 128) *counter = 0;
  }
  int b, qt, kt;
  if (job < 480) {  // off-diagonal tiles: 120 per batch
    b = job / 120;
    int r = job - b * 120;
    qt = 0;
    while (r >= 15 - qt) { r -= 15 - qt; ++qt; }
    kt = qt + 1 + r;
  } else {          // diagonal tiles: 16 per batch
    int dj = job - 480;
    b = dj >> 4;
    qt = kt = dj & 15;
  }
  const bool diag = (kt == qt);
  const float C = 2.8853900817779268f;  // 2*log2(e)
  const float L2E = 1.4426950408889634f;
  const float* xb = x + (size_t)b * L_ * D_;
  for (int i = tid; i < 32 * D_; i += 256) {
    int r = i / D_, c = i - r * D_;
    float xq = xb[(qt * 32 + r) * D_ + c];
    XQ[r * 102 + c] = make_float2(xq, fexp2(xq * C));
    if (!diag) {
      float xk = xb[(kt * 32 + r) * D_ + c];
      XK[r * 102 + c] = make_float2(xk, fexp2(xk * C));
    }
  }
  __syncthreads();
  const float2* XKp = diag ? XQ : XK;
  const int tx = tid & 15, ty = tid >> 4;
  float s00 = 0, s01 = 0, s10 = 0, s11 = 0;
  float r00 = 0, r01 = 0, r10 = 0, r11 = 0;
  const float2* qp0 = &XQ[ty * 102];
  const float2* qp1 = &XQ[(ty + 16) * 102];
  const float2* kp0 = &XKp[tx * 102];
  const float2* kp1 = &XKp[(tx + 16) * 102];
#pragma unroll 2
  for (int d = 0; d < D_; d += 2) {  // 2 d per iter via float4 (b128) reads
    float4 A0 = *(const float4*)&qp0[d];
    float4 A1 = *(const float4*)&qp1[d];
    float4 B0 = *(const float4*)&kp0[d];
    float4 B1 = *(const float4*)&kp1[d];
    s00 += A0.x * B0.x + A0.z * B0.z;
    s01 += A0.x * B1.x + A0.z * B1.z;
    s10 += A1.x * B0.x + A1.z * B0.z;
    s11 += A1.x * B1.x + A1.z * B1.z;
    r00 += frcp(fmaf(A0.y, B0.y, 1.0f)) + frcp(fmaf(A0.w, B0.w, 1.0f));
    r01 += frcp(fmaf(A0.y, B1.y, 1.0f)) + frcp(fmaf(A0.w, B1.w, 1.0f));
    r10 += frcp(fmaf(A1.y, B0.y, 1.0f)) + frcp(fmaf(A1.w, B0.w, 1.0f));
    r11 += frcp(fmaf(A1.y, B1.y, 1.0f)) + frcp(fmaf(A1.w, B1.w, 1.0f));
  }
  float t00 = (float)D_ - 2.0f * r00;
  float t01 = (float)D_ - 2.0f * r01;
  float t10 = (float)D_ - 2.0f * r10;
  float t11 = (float)D_ - 2.0f * r11;
  float e1_00 = fexp2(fmaf(s00, L2E, -120.0f)), e1_01 = fexp2(fmaf(s01, L2E, -120.0f));
  float e1_10 = fexp2(fmaf(s10, L2E, -120.0f)), e1_11 = fexp2(fmaf(s11, L2E, -120.0f));
  float e2_00 = fexp2(fmaf(t00, L2E, -32.0f)),  e2_01 = fexp2(fmaf(t01, L2E, -32.0f));
  float e2_10 = fexp2(fmaf(t10, L2E, -32.0f)),  e2_11 = fexp2(fmaf(t11, L2E, -32.0f));
  const float L2E10 = 0.14426950408889634f;
  float e3_00 = fexp2(s00 * L2E10), e3_01 = fexp2(s01 * L2E10);
  float e3_10 = fexp2(s10 * L2E10), e3_11 = fexp2(s11 * L2E10);

  const int q0r = qt * 32 + ty, q1r = q0r + 16;
  const int k0 = kt * 32 + tx, k1 = k0 + 16;
  float* Sb = S + (size_t)b * L_ * L_;
  float* Tb = T + (size_t)b * L_ * L_;
  Sb[q0r * L_ + k0] = s00; Sb[q0r * L_ + k1] = s01;
  Sb[q1r * L_ + k0] = s10; Sb[q1r * L_ + k1] = s11;
  Tb[q0r * L_ + k0] = t00; Tb[q0r * L_ + k1] = t01;
  Tb[q1r * L_ + k0] = t10; Tb[q1r * L_ + k1] = t11;

  // ---- row Zp partials (reduce e-sums over tx within wave)
  float rs[3][2];
  rs[0][0] = e1_00 + e1_01; rs[0][1] = e1_10 + e1_11;
  rs[1][0] = e2_00 + e2_01; rs[1][1] = e2_10 + e2_11;
  rs[2][0] = e3_00 + e3_01; rs[2][1] = e3_10 + e3_11;
#pragma unroll
  for (int o = 8; o > 0; o >>= 1) {
#pragma unroll
    for (int e = 0; e < 3; ++e) {
      rs[e][0] += __shfl_xor(rs[e][0], o);
      rs[e][1] += __shfl_xor(rs[e][1], o);
    }
  }
  if (tx == 0) {
#pragma unroll
    for (int e = 0; e < 3; ++e) {
      Zp[(((size_t)b * L_ + q0r) * 16 + kt) * 3 + e] = rs[e][0];
      Zp[(((size_t)b * L_ + q1r) * 16 + kt) * 3 + e] = rs[e][1];
    }
  }

  if (diag) return;

  // ---- column Zp partials (mirror rows): shuffles over ty bits then LDS
  float cs_[3][2];
  cs_[0][0] = e1_00 + e1_10; cs_[0][1] = e1_01 + e1_11;
  cs_[1][0] = e2_00 + e2_10; cs_[1][1] = e2_01 + e2_11;
  cs_[2][0] = e3_00 + e3_10; cs_[2][1] = e3_01 + e3_11;
#pragma unroll
  for (int o = 16; o <= 32; o <<= 1) {
#pragma unroll
    for (int e = 0; e < 3; ++e) {
      cs_[e][0] += __shfl_xor(cs_[e][0], o);
      cs_[e][1] += __shfl_xor(cs_[e][1], o);
    }
  }
  __syncthreads();  // all d-loop reads of XK complete before aliasing
  float* xkf = (float*)XK;        // reuse XK space
  float* M = xkf;                 // 32*33 = 1056 floats (transpose buffer)
  float* colred = xkf + 1104;     // 4*16*6 = 384 floats
  const int wv = tid >> 6, lane = tid & 63;
  if ((lane >> 4) == 0) {
#pragma unroll
    for (int e = 0; e < 3; ++e) {
      colred[wv * 96 + tx * 6 + e * 2 + 0] = cs_[e][0];
      colred[wv * 96 + tx * 6 + e * 2 + 1] = cs_[e][1];
    }
  }
  __syncthreads();  // colred ready
  if (tid < 96) {
    int txx = tid / 6, j = tid - txx * 6;
    float v = colred[0 * 96 + txx * 6 + j] + colred[1 * 96 + txx * 6 + j] +
              colred[2 * 96 + txx * 6 + j] + colred[3 * 96 + txx * 6 + j];
    int e = j >> 1, half = j & 1;
    int krow = kt * 32 + txx + half * 16;
    Zp[(((size_t)b * L_ + krow) * 16 + qt) * 3 + e] = v;
  }
  // ---- mirror stores via LDS transpose (coalesced rows); M disjoint from colred
  const int mo = ty * 33 + tx;
  M[mo] = s00; M[mo + 16] = s01;
  M[mo + 16 * 33] = s10; M[mo + 16 * 33 + 16] = s11;
  __syncthreads();
#pragma unroll
  for (int j = 0; j < 4; ++j) {
    int idx = tid + 256 * j, kr = idx >> 5, qc = idx & 31;
    Sb[(kt * 32 + kr) * L_ + qt * 32 + qc] = M[qc * 33 + kr];
  }
  __syncthreads();
  M[mo] = t00; M[mo + 16] = t01;
  M[mo + 16 * 33] = t10; M[mo + 16 * 33 + 16] = t11;
  __syncthreads();
#pragma unroll
  for (int j = 0; j < 4; ++j) {
    int idx = tid + 256 * j, kr = idx >> 5, qc = idx & 31;
    Tb[(kt * 32 + kr) * L_ + qt * 32 + qc] = M[qc * 33 + kr];
  }
}

// ---------------------------------------------------------------------------
// K2 v2: fused normalize + PV + residual + conv + maxpool + linear.
// Same job decomposition as round 10 (512 blocks; block = (b, q0) owning
// conv outputs t=q0+2..q0+5, 6 local PV rows; block q0=0 adds t=0,1).
// Register-blocked rewrite to cut LDS/VMEM instruction counts:
//   PV: thread = (dq=tid&31 -> d=4dq, active dq<25; ks=tid>>5 of 8 k-slices).
//       Each P b128 read feeds 4d x 4k FMAs (4x fewer LDS reads); x loads are
//       float4 (4x fewer VMEM instr). Slice pairs combined via shfl_xor(32),
//       4 wave-partials summed through R[4][6][104].
//   Conv: thread = (c=tid>>3, ds=tid&7); weights hoisted to 12 float4 regs;
//       each thread accumulates all 4-6 t outputs over its d-slice
//       (j = ds+8m, m<4, j<25); reduce over ds via shfl_xor(1,2,4).
// ---------------------------------------------------------------------------
__global__ __launch_bounds__(256) void k2_fused(const float* __restrict__ x,
    const float* __restrict__ S, const float* __restrict__ T,
    const float* __restrict__ Zp, const float* __restrict__ attw,
    const float* __restrict__ w1, const float* __restrict__ b1,
    const float* __restrict__ w2, const float* __restrict__ b2,
    const float* __restrict__ w3, const float* __restrict__ b3,
    const float* __restrict__ lw, const float* __restrict__ lb,
    float* __restrict__ pooled, int* __restrict__ counter,
    float* __restrict__ out) {
  __shared__ float wl[30 * 304];   // zero-padded right-aligned ws=3 weights
  __shared__ float cc[6][3];
  __shared__ float P[6][512];
  __shared__ float R[4][6][104];   // 4 wave-partials of PV
  __shared__ float X2L[6][104];
  __shared__ int lastFlag;
  const int tid = threadIdx.x;
  const int b = blockIdx.x >> 7, q0 = (blockIdx.x & 127) * 4;
  const float L2E = 1.4426950408889634f, L2E10 = 0.14426950408889634f;

  // ---- stage conv weights (validated mapping)
  for (int i = tid; i < 30 * 300; i += 256) {
    int c = i / 300, rest = i - c * 300;
    int h = rest / D_, dd = rest - h * D_;
    int ws = 1 + c / 10;
    int hh = h - (3 - ws);
    float wv = 0.0f;
    if (hh >= 0) {
      if (ws == 1)      wv = w1[c * D_ + dd];
      else if (ws == 2) wv = w2[(c - 10) * 2 * D_ + hh * D_ + dd];
      else              wv = w3[(c - 20) * 3 * D_ + hh * D_ + dd];
    }
    wl[c * 304 + h * D_ + dd] = wv;
  }
  // ---- softmax coefficients for 6 rows (rows >= L get c=0)
  if (tid < 18) {
    int row = tid / 3, j = tid - row * 3;
    int qr = q0 + row;
    float cv = 0.0f;
    if (qr < L_) {
      const float* zp = Zp + ((size_t)b * L_ + qr) * 16 * 3 + j;
      float z = 0.0f;
#pragma unroll
      for (int t = 0; t < 16; ++t) z += zp[t * 3];
      float winv = frcp(attw[0] + attw[1] + attw[2]);
      cv = attw[j] * winv * frcp(z);
    }
    cc[row][j] = cv;
  }
  __syncthreads();

  // ---- P-form: 6 rows x 512 k (bit-identical exps to K1's Zp path)
  for (int i = tid; i < 6 * 512; i += 256) {
    int row = i >> 9, kk = i & 511;
    int qr = q0 + row;
    float pv = 0.0f;
    if (qr < L_) {
      size_t o = ((size_t)b * L_ + qr) * (size_t)L_ + kk;
      float s = S[o], t = T[o];
      pv = cc[row][0] * fexp2(fmaf(s, L2E, -120.0f)) +
           cc[row][1] * fexp2(fmaf(t, L2E, -32.0f)) +
           cc[row][2] * fexp2(s * L2E10);
    }
    P[row][kk] = pv;
  }
  __syncthreads();

  // ---- PV: d-quad register blocking
  const int dq = tid & 31, ks = tid >> 5;   // ks in 0..7, 64 k each
  float4 acc[6];
#pragma unroll
  for (int r = 0; r < 6; ++r) acc[r] = make_float4(0.f, 0.f, 0.f, 0.f);
  if (dq < 25) {
    const float* xb = x + (size_t)b * L_ * D_;
    const int kbase = ks * 64;
    for (int g = 0; g < 16; ++g) {
      int k = kbase + g * 4;
      float4 xv0 = *(const float4*)&xb[(k + 0) * D_ + 4 * dq];
      float4 xv1 = *(const float4*)&xb[(k + 1) * D_ + 4 * dq];
      float4 xv2 = *(const float4*)&xb[(k + 2) * D_ + 4 * dq];
      float4 xv3 = *(const float4*)&xb[(k + 3) * D_ + 4 * dq];
#pragma unroll
      for (int r = 0; r < 6; ++r) {
        float4 p = *(const float4*)&P[r][k];
        acc[r].x += p.x * xv0.x + p.y * xv1.x + p.z * xv2.x + p.w * xv3.x;
        acc[r].y += p.x * xv0.y + p.y * xv1.y + p.z * xv2.y + p.w * xv3.y;
        acc[r].z += p.x * xv0.z + p.y * xv1.z + p.z * xv2.z + p.w * xv3.z;
        acc[r].w += p.x * xv0.w + p.y * xv1.w + p.z * xv2.w + p.w * xv3.w;
      }
    }
  }
  // combine slice pairs (lanes l <-> l+32 share dq, ks differs by 1)
#pragma unroll
  for (int r = 0; r < 6; ++r) {
    acc[r].x += __shfl_xor(acc[r].x, 32);
    acc[r].y += __shfl_xor(acc[r].y, 32);
    acc[r].z += __shfl_xor(acc[r].z, 32);
    acc[r].w += __shfl_xor(acc[r].w, 32);
  }
  const int wv = tid >> 6;
  if ((tid & 63) < 32 && dq < 25) {
#pragma unroll
    for (int r = 0; r < 6; ++r)
      *(float4*)&R[wv][r][4 * dq] = acc[r];
  }
  __syncthreads();

  // ---- X2 (LDS only): src + attn; zero for rows >= L
  for (int i = tid; i < 6 * D_; i += 256) {
    int r = i / D_, dd = i - r * D_;
    int qr = q0 + r;
    float v = 0.0f;
    if (qr < L_)
      v = x[((size_t)b * L_ + qr) * D_ + dd] +
          R[0][r][dd] + R[1][r][dd] + R[2][r][dd] + R[3][r][dd];
    X2L[r][dd] = v;
  }
  __syncthreads();

  // ---- conv: thread (c = tid>>3, ds = tid&7), weights in registers
  const int c = tid >> 3, ds = tid & 7;
  const int cS = (c < 30) ? c : 0;           // clamp for safe LDS addressing
  const int wsz = 1 + cS / 10;
  float4 wr[3][4];
#pragma unroll
  for (int h = 0; h < 3; ++h)
#pragma unroll
    for (int m = 0; m < 4; ++m) {
      int j = ds + 8 * m;
      wr[h][m] = (j < 25) ? *(const float4*)&wl[cS * 304 + h * D_ + 4 * j]
                          : make_float4(0.f, 0.f, 0.f, 0.f);
    }
  float tacc[6];
#pragma unroll
  for (int tt = 0; tt < 6; ++tt) {
    float a = 0.0f;
    int t = (tt < 4) ? (q0 + 2 + tt) : ((q0 == 0) ? tt - 4 : -1);
    if (t >= 0) {
#pragma unroll
      for (int h = 0; h < 3; ++h) {
        int idx = t - 2 + h - q0;            // in [-2, 5]; valid rows >= 0
        if (idx >= 0) {
#pragma unroll
          for (int m = 0; m < 4; ++m) {
            int j = ds + 8 * m;
            if (j < 25) {
              float4 xv = *(const float4*)&X2L[idx][4 * j];
              float4 wv2 = wr[h][m];
              a += xv.x * wv2.x + xv.y * wv2.y + xv.z * wv2.z + xv.w * wv2.w;
            }
          }
        }
      }
    }
    tacc[tt] = a;
  }
#pragma unroll
  for (int tt = 0; tt < 6; ++tt) {
    tacc[tt] += __shfl_xor(tacc[tt], 1);
    tacc[tt] += __shfl_xor(tacc[tt], 2);
    tacc[tt] += __shfl_xor(tacc[tt], 4);
  }
  if (c < 30 && ds == 0) {
    float bias = (wsz == 1) ? b1[c] : (wsz == 2 ? b2[c - 10] : b3[c - 20]);
    float vm = 0.0f;
#pragma unroll
    for (int tt = 0; tt < 6; ++tt) {
      int t = (tt < 4) ? (q0 + 2 + tt) : ((q0 == 0) ? tt - 4 : -1);
      if (t >= 0 && t < L_ + wsz - 1) vm = fmaxf(vm, fmaxf(tacc[tt] + bias, 0.0f));
    }
    atomicMax(reinterpret_cast<int*>(&pooled[b * 30 + c]), __float_as_int(vm));
  }

  // ---- arrival counter: last of 512 blocks computes the linear head
  __syncthreads();
  if (tid == 0) {
    __threadfence();
    int old = atomicAdd(counter, 1);
    lastFlag = (old == 512 - 1);
  }
  __syncthreads();
  if (lastFlag && tid < B_ * 2) {
    int bb = tid >> 1, j = tid & 1;
    float acc2 = lb[j];
    int* pI = reinterpret_cast<int*>(pooled);
#pragma unroll
    for (int cch = 0; cch < 30; ++cch) {
      int pi = atomicMax(&pI[bb * 30 + cch], 0);  // coherent read (values >= 0)
      acc2 = fmaf(__int_as_float(pi), lw[cch * 2 + j], acc2);
    }
    out[bb * 2 + j] = acc2;
  }
}

extern "C" void kernel_launch(void* const* d_in, const int* in_sizes, int n_in,
                              void* d_out, int out_size, void* d_ws, size_t ws_size,
                              hipStream_t stream) {
  const float* src  = (const float*)d_in[0];
  const float* attw = (const float*)d_in[1];
  const float* w1   = (const float*)d_in[2];
  const float* b1   = (const float*)d_in[3];
  const float* w2   = (const float*)d_in[4];
  const float* b2   = (const float*)d_in[5];
  const float* w3   = (const float*)d_in[6];
  const float* b3   = (const float*)d_in[7];
  const float* lw   = (const float*)d_in[8];
  const float* lb   = (const float*)d_in[9];

  // ws: S | T (1,048,576 f32 each) | Zp (98,304) | pooled(128) | counter
  float* S  = (float*)d_ws;
  float* T  = S + (size_t)B_ * L_ * L_;
  float* Zp = T + (size_t)B_ * L_ * L_;
  float* PL = Zp + (size_t)B_ * L_ * 16 * 3;
  int* counter = (int*)(PL + 128);
  float* out = (float*)d_out;

  hipLaunchKernelGGL(k1_scores, dim3(544), dim3(256), 0, stream,
                     src, S, T, Zp, counter, PL);
  hipLaunchKernelGGL(k2_fused, dim3(512), dim3(256), 0, stream,
                     src, S, T, Zp, attw, w1, b1, w2, b2, w3, b3, lw, lb,
                     PL, counter, out);
}